// Round 5
// baseline (8212.122 us; speedup 1.0000x reference)
//
#include <hip/hip_runtime.h>
#include <cstddef>
#include <cstdint>
#include <math.h>

// Problem constants (B=2, S=2048, D=2048, H=16, hd=128)
#define NB 2
#define NS 2048
#define ND 2048
#define NH 16
#define HD 128

// ---------------------------------------------------------------------------
// Tiled fp32 GEMM: C[M,N] = A[M,K] @ B[K,N]. 128x128 tile, K-step 16,
// 256 threads, 8x8 accumulator per thread (2x2 groups of 4x4, groups 64
// apart). LDS rows padded to 132 floats (stride 132 % 32 = 4) so b128
// stores/reads are <=2-way bank-aliased (free).
// Register-prefetch pipeline: global loads for tile k+1 issue right after
// tile k's LDS stores, so HBM latency hides under the 16x64-FMA compute.
// Optional fused RoPE epilogue for the QKV projection (rotates q,k; v as-is).
// ---------------------------------------------------------------------------
template <bool ROPE>
__global__ __launch_bounds__(256) void gemm_f32_kernel(
    const float* __restrict__ A, const float* __restrict__ Bm,
    float* __restrict__ C, int M, int N, int K) {
  __shared__ float As[16][132];  // [k][m] (transposed for frag reads)
  __shared__ float Bs[16][132];  // [k][n]
  const int tid = threadIdx.x;
  const int m0 = blockIdx.y * 128;
  const int n0 = blockIdx.x * 128;
  const int tr = tid >> 4;             // 0..15 (row group)
  const int tc = tid & 15;             // 0..15 (col group)
  const int la_r = tid >> 1;           // A load: row 0..127
  const int la_c = (tid & 1) << 3;     // A load: col 0 or 8
  const int lb_r = tid >> 4;           // B load: row 0..15
  const int lb_c = (tid & 15) << 3;    // B load: col 0,8,..,120

  const float* Aptr = A + (size_t)(m0 + la_r) * K + la_c;
  const float* Bptr = Bm + (size_t)lb_r * N + n0 + lb_c;

  float acc[8][8] = {};

  // prologue: load tile k0=0 into registers
  float4 av0 = *(const float4*)(Aptr);
  float4 av1 = *(const float4*)(Aptr + 4);
  float4 bv0 = *(const float4*)(Bptr);
  float4 bv1 = *(const float4*)(Bptr + 4);

  for (int k0 = 0; k0 < K; k0 += 16) {
    __syncthreads();  // previous tile fully consumed
    // A transposed into LDS: As[k][m]
    As[la_c + 0][la_r] = av0.x;
    As[la_c + 1][la_r] = av0.y;
    As[la_c + 2][la_r] = av0.z;
    As[la_c + 3][la_r] = av0.w;
    As[la_c + 4][la_r] = av1.x;
    As[la_c + 5][la_r] = av1.y;
    As[la_c + 6][la_r] = av1.z;
    As[la_c + 7][la_r] = av1.w;
    *(float4*)&Bs[lb_r][lb_c] = bv0;
    *(float4*)&Bs[lb_r][lb_c + 4] = bv1;
    __syncthreads();
    // prefetch next K-tile while computing this one
    if (k0 + 16 < K) {
      const float* An = Aptr + k0 + 16;
      const float* Bn = Bptr + (size_t)(k0 + 16) * N;
      av0 = *(const float4*)(An);
      av1 = *(const float4*)(An + 4);
      bv0 = *(const float4*)(Bn);
      bv1 = *(const float4*)(Bn + 4);
    }
#pragma unroll
    for (int kk = 0; kk < 16; ++kk) {
      float a[8], b[8];
      *(float4*)&a[0] = *(const float4*)&As[kk][tr << 2];
      *(float4*)&a[4] = *(const float4*)&As[kk][64 + (tr << 2)];
      *(float4*)&b[0] = *(const float4*)&Bs[kk][tc << 2];
      *(float4*)&b[4] = *(const float4*)&Bs[kk][64 + (tc << 2)];
#pragma unroll
      for (int i = 0; i < 8; ++i)
#pragma unroll
        for (int j = 0; j < 8; ++j) acc[i][j] = fmaf(a[i], b[j], acc[i][j]);
    }
  }

  if (ROPE) {
    // slab: 0=q, 1=k, 2=v. n0 is a multiple of 128, slabs 2048 wide, so the
    // whole 128-wide tile sits in one slab (uniform, no divergence).
    if ((n0 >> 11) < 2) {
#pragma unroll
      for (int g = 0; g < 2; ++g) {
        const int col = n0 + g * 64 + (tc << 2);
        const int d0 = col & (HD - 1);  // multiple of 4
        const int p0 = d0 >> 1;         // rope pair index of cols (0,1)
        const float invf0 = powf(10000.f, -(float)p0 * (1.f / 64.f));
        const float invf1 = powf(10000.f, -(float)(p0 + 1) * (1.f / 64.f));
#pragma unroll
        for (int rg = 0; rg < 2; ++rg) {
#pragma unroll
          for (int i = 0; i < 4; ++i) {
            const int row = m0 + rg * 64 + (tr << 2) + i;
            const int spos = row & (NS - 1);
            float s0, c0, s1, c1;
            sincosf((float)spos * invf0, &s0, &c0);
            sincosf((float)spos * invf1, &s1, &c1);
            float* ar = &acc[rg * 4 + i][g * 4];
            const float xe0 = ar[0], xo0 = ar[1];
            const float xe1 = ar[2], xo1 = ar[3];
            ar[0] = xe0 * c0 - xo0 * s0;
            ar[1] = xe0 * s0 + xo0 * c0;
            ar[2] = xe1 * c1 - xo1 * s1;
            ar[3] = xe1 * s1 + xo1 * c1;
          }
        }
      }
    }
  }
#pragma unroll
  for (int rg = 0; rg < 2; ++rg) {
#pragma unroll
    for (int i = 0; i < 4; ++i) {
      const size_t row = m0 + rg * 64 + (tr << 2) + i;
      float* Crow = C + row * N + n0;
      float4 v0 = make_float4(acc[rg * 4 + i][0], acc[rg * 4 + i][1],
                              acc[rg * 4 + i][2], acc[rg * 4 + i][3]);
      float4 v1 = make_float4(acc[rg * 4 + i][4], acc[rg * 4 + i][5],
                              acc[rg * 4 + i][6], acc[rg * 4 + i][7]);
      *(float4*)(Crow + (tc << 2)) = v0;
      *(float4*)(Crow + 64 + (tc << 2)) = v1;
    }
  }
}

// ---------------------------------------------------------------------------
// Flash attention (causal), fp32. Block = 256 threads = 4 waves, handles 64
// q-rows of one (b,h). Each wave owns 16 rows; 4 lanes per row, each lane
// holds the interleaved hd-slice d = 4*i + sub (i=0..31) so LDS reads of
// K/V are 4 consecutive dwords per group (conflict-free, 16-way broadcast).
// K/V tiles of 64 rows staged in LDS (64 KiB total).
// qkv layout: [B, S, 3*D] with rope already applied to q,k.
// O layout: [B, S, H*hd] (= attn input to the output GEMM).
// ---------------------------------------------------------------------------
__global__ __launch_bounds__(256) void flash_attn_kernel(
    const float* __restrict__ qkv, float* __restrict__ O) {
  __shared__ float Ks[64][HD];
  __shared__ float Vs[64][HD];
  const int tid = threadIdx.x;
  const int wave = tid >> 6;
  const int lane = tid & 63;
  const int rw = lane >> 2;   // row within wave 0..15
  const int sub = lane & 3;   // hd-slice id
  const int qt = blockIdx.x;
  const int bh = blockIdx.y;
  const int b = bh >> 4;
  const int h = bh & 15;
  const int qrow = (qt << 6) + (wave << 4) + rw;  // position in sequence
  const size_t rowstride = 3 * ND;
  const float* Qbase = qkv + (size_t)b * NS * rowstride + (size_t)h * HD;
  const float* Kbase = Qbase + ND;
  const float* Vbase = Qbase + 2 * ND;

  float q[32];
#pragma unroll
  for (int i = 0; i < 32; ++i)
    q[i] = Qbase[(size_t)qrow * rowstride + 4 * i + sub];

  float o[32];
#pragma unroll
  for (int i = 0; i < 32; ++i) o[i] = 0.f;
  float m = -INFINITY, l = 0.f;
  const float scale = 0.088388347648318447f;  // 1/sqrt(128)

  for (int kt = 0; kt <= qt; ++kt) {
    __syncthreads();  // previous tile fully consumed before overwrite
#pragma unroll
    for (int p = 0; p < 8; ++p) {
      const int flat = (p * 256 + tid) * 4;
      const int r = flat >> 7;
      const int c = flat & (HD - 1);
      *(float4*)&Ks[r][c] =
          *(const float4*)(Kbase + (size_t)((kt << 6) + r) * rowstride + c);
      *(float4*)&Vs[r][c] =
          *(const float4*)(Vbase + (size_t)((kt << 6) + r) * rowstride + c);
    }
    __syncthreads();

    float sarr[64];
#pragma unroll
    for (int kc = 0; kc < 64; ++kc) {
      float s = 0.f;
#pragma unroll
      for (int i = 0; i < 32; ++i) s = fmaf(q[i], Ks[kc][4 * i + sub], s);
      // reduce partial dot across the 4 lanes of this row
      s += __shfl_xor(s, 1);
      s += __shfl_xor(s, 2);
      s *= scale;
      if ((kt << 6) + kc > qrow) s = -INFINITY;  // causal mask (diag tile)
      sarr[kc] = s;
    }
    float tmax = sarr[0];
#pragma unroll
    for (int kc = 1; kc < 64; ++kc) tmax = fmaxf(tmax, sarr[kc]);
    const float mn = fmaxf(m, tmax);           // finite: kc=0 always valid
    const float alpha = __expf(m - mn);        // first tile: exp(-inf)=0
    float psum = 0.f;
#pragma unroll
    for (int kc = 0; kc < 64; ++kc) {
      const float pv = __expf(sarr[kc] - mn);  // masked -> exp(-inf)=0
      sarr[kc] = pv;
      psum += pv;
    }
    l = l * alpha + psum;
    m = mn;
#pragma unroll
    for (int i = 0; i < 32; ++i) o[i] *= alpha;
#pragma unroll
    for (int kc = 0; kc < 64; ++kc) {
      const float pv = sarr[kc];
#pragma unroll
      for (int i = 0; i < 32; ++i)
        o[i] = fmaf(pv, Vs[kc][4 * i + sub], o[i]);
    }
  }
  const float inv_l = 1.f / l;
  float* Orow = O + ((size_t)b * NS + qrow) * ND + (size_t)h * HD;
#pragma unroll
  for (int i = 0; i < 32; ++i) Orow[4 * i + sub] = o[i] * inv_l;
}

// ---------------------------------------------------------------------------
// Launch: qkv+rope GEMM -> flash attention -> output GEMM.
// Workspace: qkv [B,S,3D] fp32 (96 MiB) + attn [B,S,D] fp32 (32 MiB).
// ---------------------------------------------------------------------------
extern "C" void kernel_launch(void* const* d_in, const int* in_sizes, int n_in,
                              void* d_out, int out_size, void* d_ws,
                              size_t ws_size, hipStream_t stream) {
  const float* x = (const float*)d_in[0];
  const float* Wqkv = (const float*)d_in[1];
  const float* Wo = (const float*)d_in[2];
  float* out = (float*)d_out;
  float* qkv = (float*)d_ws;                           // 25165824 floats
  float* attn = qkv + (size_t)NB * NS * 3 * ND;        // 8388608 floats

  gemm_f32_kernel<true><<<dim3(3 * ND / 128, NB * NS / 128), 256, 0, stream>>>(
      x, Wqkv, qkv, NB * NS, 3 * ND, ND);
  flash_attn_kernel<<<dim3(NS / 64, NB * NH), 256, 0, stream>>>(qkv, attn);
  gemm_f32_kernel<false><<<dim3(ND / 128, NB * NS / 128), 256, 0, stream>>>(
      attn, Wo, out, NB * NS, ND, ND);
}

// Round 6
// 1814.200 us; speedup vs baseline: 4.5266x; 4.5266x over previous
//
#include <hip/hip_runtime.h>
#include <cstddef>
#include <cstdint>
#include <math.h>

// Problem constants (B=2, S=2048, D=2048, H=16, hd=128)
#define NB 2
#define NS 2048
#define ND 2048
#define NH 16
#define HD 128

typedef __attribute__((ext_vector_type(8))) short short8v;   // 8 bf16 (4 VGPR)
typedef __attribute__((ext_vector_type(4))) float float4v;   // MFMA acc

#define MFMA16(A, B, C) __builtin_amdgcn_mfma_f32_16x16x32_bf16(A, B, C, 0, 0, 0)

// Split fp32 into bf16 hi + bf16 lo (x ~= hi + lo, rel err ~2^-17).
__device__ __forceinline__ void split_bf16(float x, short& hi, short& lo) {
  unsigned u = __float_as_uint(x);
  unsigned hb = (u + 0x7FFFu + ((u >> 16) & 1u)) >> 16;
  float hif = __uint_as_float(hb << 16);
  float r = x - hif;
  unsigned ul = __float_as_uint(r);
  hi = (short)hb;
  lo = (short)((ul + 0x7FFFu + ((ul >> 16) & 1u)) >> 16);
}

// ---------------------------------------------------------------------------
// Tiled fp32 GEMM (unchanged from validated round-5 kernel).
// ---------------------------------------------------------------------------
template <bool ROPE>
__global__ __launch_bounds__(256) void gemm_f32_kernel(
    const float* __restrict__ A, const float* __restrict__ Bm,
    float* __restrict__ C, int M, int N, int K) {
  __shared__ float As[16][132];
  __shared__ float Bs[16][132];
  const int tid = threadIdx.x;
  const int m0 = blockIdx.y * 128;
  const int n0 = blockIdx.x * 128;
  const int tr = tid >> 4;
  const int tc = tid & 15;
  const int la_r = tid >> 1;
  const int la_c = (tid & 1) << 3;
  const int lb_r = tid >> 4;
  const int lb_c = (tid & 15) << 3;

  const float* Aptr = A + (size_t)(m0 + la_r) * K + la_c;
  const float* Bptr = Bm + (size_t)lb_r * N + n0 + lb_c;

  float acc[8][8] = {};

  float4 av0 = *(const float4*)(Aptr);
  float4 av1 = *(const float4*)(Aptr + 4);
  float4 bv0 = *(const float4*)(Bptr);
  float4 bv1 = *(const float4*)(Bptr + 4);

  for (int k0 = 0; k0 < K; k0 += 16) {
    __syncthreads();
    As[la_c + 0][la_r] = av0.x;
    As[la_c + 1][la_r] = av0.y;
    As[la_c + 2][la_r] = av0.z;
    As[la_c + 3][la_r] = av0.w;
    As[la_c + 4][la_r] = av1.x;
    As[la_c + 5][la_r] = av1.y;
    As[la_c + 6][la_r] = av1.z;
    As[la_c + 7][la_r] = av1.w;
    *(float4*)&Bs[lb_r][lb_c] = bv0;
    *(float4*)&Bs[lb_r][lb_c + 4] = bv1;
    __syncthreads();
    if (k0 + 16 < K) {
      const float* An = Aptr + k0 + 16;
      const float* Bn = Bptr + (size_t)(k0 + 16) * N;
      av0 = *(const float4*)(An);
      av1 = *(const float4*)(An + 4);
      bv0 = *(const float4*)(Bn);
      bv1 = *(const float4*)(Bn + 4);
    }
#pragma unroll
    for (int kk = 0; kk < 16; ++kk) {
      float a[8], b[8];
      *(float4*)&a[0] = *(const float4*)&As[kk][tr << 2];
      *(float4*)&a[4] = *(const float4*)&As[kk][64 + (tr << 2)];
      *(float4*)&b[0] = *(const float4*)&Bs[kk][tc << 2];
      *(float4*)&b[4] = *(const float4*)&Bs[kk][64 + (tc << 2)];
#pragma unroll
      for (int i = 0; i < 8; ++i)
#pragma unroll
        for (int j = 0; j < 8; ++j) acc[i][j] = fmaf(a[i], b[j], acc[i][j]);
    }
  }

  if (ROPE) {
    if ((n0 >> 11) < 2) {
#pragma unroll
      for (int g = 0; g < 2; ++g) {
        const int col = n0 + g * 64 + (tc << 2);
        const int d0 = col & (HD - 1);
        const int p0 = d0 >> 1;
        const float invf0 = powf(10000.f, -(float)p0 * (1.f / 64.f));
        const float invf1 = powf(10000.f, -(float)(p0 + 1) * (1.f / 64.f));
#pragma unroll
        for (int rg = 0; rg < 2; ++rg) {
#pragma unroll
          for (int i = 0; i < 4; ++i) {
            const int row = m0 + rg * 64 + (tr << 2) + i;
            const int spos = row & (NS - 1);
            float s0, c0, s1, c1;
            sincosf((float)spos * invf0, &s0, &c0);
            sincosf((float)spos * invf1, &s1, &c1);
            float* ar = &acc[rg * 4 + i][g * 4];
            const float xe0 = ar[0], xo0 = ar[1];
            const float xe1 = ar[2], xo1 = ar[3];
            ar[0] = xe0 * c0 - xo0 * s0;
            ar[1] = xe0 * s0 + xo0 * c0;
            ar[2] = xe1 * c1 - xo1 * s1;
            ar[3] = xe1 * s1 + xo1 * c1;
          }
        }
      }
    }
  }
#pragma unroll
  for (int rg = 0; rg < 2; ++rg) {
#pragma unroll
    for (int i = 0; i < 4; ++i) {
      const size_t row = m0 + rg * 64 + (tr << 2) + i;
      float* Crow = C + row * N + n0;
      float4 v0 = make_float4(acc[rg * 4 + i][0], acc[rg * 4 + i][1],
                              acc[rg * 4 + i][2], acc[rg * 4 + i][3]);
      float4 v1 = make_float4(acc[rg * 4 + i][4], acc[rg * 4 + i][5],
                              acc[rg * 4 + i][6], acc[rg * 4 + i][7]);
      *(float4*)(Crow + (tc << 2)) = v0;
      *(float4*)(Crow + 64 + (tc << 2)) = v1;
    }
  }
}

// ---------------------------------------------------------------------------
// Flash attention via split-bf16 MFMA (16x16x32). Block = 512 threads =
// 8 waves = 128 q-rows of one (b,h); KV tiles of 32.
//  - K staged hi/lo row-major [32][136] (pad: stride 272B, 16B-aligned).
//  - V staged hi/lo TRANSPOSED [128][40] so PV's B-operand reads are b128.
//  - Swapped QK^T: S^T = mfma(A=K, B=Q); lane (g,r) holds S[kv=16f+4g+j][q=r].
//  - Softmax per q-row: in-lane reduce + shfl_xor(16,32) across the 4 lanes.
//  - P split hi/lo -> per-wave LDS buffer -> A-operand of PV mfma.
//  - acc layout: lane holds O[q=4g+j][hd=16*hf+r].
// ---------------------------------------------------------------------------
__global__ __launch_bounds__(512) void flash_attn_mfma(
    const float* __restrict__ qkv, float* __restrict__ O) {
  __shared__ short Khi[32][136];
  __shared__ short Klo[32][136];
  __shared__ short Vthi[128][40];
  __shared__ short Vtlo[128][40];
  __shared__ short Phi[8][16][40];
  __shared__ short Plo[8][16][40];

  const int tid = threadIdx.x;
  const int lane = tid & 63;
  const int wave = tid >> 6;           // 0..7
  const int g = lane >> 4;             // 0..3
  const int r = lane & 15;             // 0..15
  const int qtile = 15 - blockIdx.x;   // heavy q-tiles dispatched first
  const int bh = blockIdx.y;           // 0..31
  const int b = bh >> 4, h = bh & 15;
  const int qb = qtile << 7;           // block's first q row
  const int qw = qb + (wave << 4);     // wave's first q row
  const size_t row3d = 3 * ND;
  const float* base = qkv + (size_t)b * NS * row3d + (size_t)h * HD;
  const float* Kg = base + ND;
  const float* Vg = base + 2 * ND;

  // ---- Q fragments (scaled by 1/sqrt(hd)), split hi/lo ----
  const float scale = 0.088388347648318447f;
  const float* Qrow = base + (size_t)(qw + r) * row3d;
  short8v qhi[4], qlo[4];
#pragma unroll
  for (int hf = 0; hf < 4; ++hf) {
    const float* p = Qrow + 32 * hf + 8 * g;
    float4 x0 = *(const float4*)(p);
    float4 x1 = *(const float4*)(p + 4);
    float xs[8] = {x0.x, x0.y, x0.z, x0.w, x1.x, x1.y, x1.z, x1.w};
#pragma unroll
    for (int i = 0; i < 8; ++i) {
      short hi_, lo_;
      split_bf16(xs[i] * scale, hi_, lo_);
      qhi[hf][i] = hi_;
      qlo[hf][i] = lo_;
    }
  }

  float4v acc[8];
#pragma unroll
  for (int i = 0; i < 8; ++i) acc[i] = (float4v){0.f, 0.f, 0.f, 0.f};
  float m_run = -INFINITY;
  float l_run = 0.f;

  // staging maps
  const int skv = tid >> 4;            // K: row 0..31
  const int shd = (tid & 15) << 3;     // K: col 0..120 step 8
  const int vkv = (tid & 15) << 1;     // V: kv pair base (even)
  const int vhd = (tid >> 4) << 2;     // V: hd chunk of 4 (0..124)
  const int ntiles = (qtile + 1) << 2;

  for (int t = 0; t < ntiles; ++t) {
    const int kvb = t << 5;  // tile's first kv row
    __syncthreads();
    {  // ---- stage K tile (split hi/lo), rows coalesced ----
      const float* kr = Kg + (size_t)(kvb + skv) * row3d + shd;
#pragma unroll
      for (int u = 0; u < 2; ++u) {
        float4 v = *(const float4*)(kr + 4 * u);
        short h0, l0, h1, l1, h2, l2, h3, l3;
        split_bf16(v.x, h0, l0);
        split_bf16(v.y, h1, l1);
        split_bf16(v.z, h2, l2);
        split_bf16(v.w, h3, l3);
        *(int2*)&Khi[skv][shd + 4 * u] = make_int2(
            (int)(unsigned short)h0 | ((int)(unsigned short)h1 << 16),
            (int)(unsigned short)h2 | ((int)(unsigned short)h3 << 16));
        *(int2*)&Klo[skv][shd + 4 * u] = make_int2(
            (int)(unsigned short)l0 | ((int)(unsigned short)l1 << 16),
            (int)(unsigned short)l2 | ((int)(unsigned short)l3 << 16));
      }
    }
    {  // ---- stage V transposed (split hi/lo), kv pairs packed as b32 ----
      const float* v0p = Vg + (size_t)(kvb + vkv) * row3d + vhd;
      const float* v1p = v0p + row3d;
      float4 a0 = *(const float4*)(v0p);
      float4 b0 = *(const float4*)(v1p);
      float e0[4] = {a0.x, a0.y, a0.z, a0.w};
      float e1[4] = {b0.x, b0.y, b0.z, b0.w};
#pragma unroll
      for (int e = 0; e < 4; ++e) {
        short h0, l0, h1, l1;
        split_bf16(e0[e], h0, l0);
        split_bf16(e1[e], h1, l1);
        *(int*)&Vthi[vhd + e][vkv] =
            (int)(unsigned short)h0 | ((int)(unsigned short)h1 << 16);
        *(int*)&Vtlo[vhd + e][vkv] =
            (int)(unsigned short)l0 | ((int)(unsigned short)l1 << 16);
      }
    }
    __syncthreads();

    if (kvb <= qw + 15) {  // wave has at least one unmasked q-row this tile
      // ---- S^T = K * Q ----
      float4v s4[2];
#pragma unroll
      for (int f = 0; f < 2; ++f) s4[f] = (float4v){0.f, 0.f, 0.f, 0.f};
#pragma unroll
      for (int f = 0; f < 2; ++f) {
#pragma unroll
        for (int hf = 0; hf < 4; ++hf) {
          short8v ka = *(const short8v*)&Khi[16 * f + r][32 * hf + 8 * g];
          short8v kb = *(const short8v*)&Klo[16 * f + r][32 * hf + 8 * g];
          s4[f] = MFMA16(ka, qhi[hf], s4[f]);
          s4[f] = MFMA16(ka, qlo[hf], s4[f]);
          s4[f] = MFMA16(kb, qhi[hf], s4[f]);
        }
      }
      // ---- causal mask (diagonal region only) ----
      const int qglob = qw + r;
      if (kvb + 31 > qw) {
#pragma unroll
        for (int f = 0; f < 2; ++f)
#pragma unroll
          for (int j = 0; j < 4; ++j)
            if (kvb + 16 * f + 4 * g + j > qglob) s4[f][j] = -INFINITY;
      }
      // ---- online softmax (per q-row: in-lane + lanes r, r+16, r+32, r+48) --
      float tmax = s4[0][0];
#pragma unroll
      for (int f = 0; f < 2; ++f)
#pragma unroll
        for (int j = 0; j < 4; ++j) tmax = fmaxf(tmax, s4[f][j]);
      tmax = fmaxf(tmax, __shfl_xor(tmax, 16));
      tmax = fmaxf(tmax, __shfl_xor(tmax, 32));
      const float mnew = fmaxf(m_run, tmax);
      const float alpha = __expf(m_run - mnew);
      float psum = 0.f;
      short ph[8], pl[8];
#pragma unroll
      for (int f = 0; f < 2; ++f)
#pragma unroll
        for (int j = 0; j < 4; ++j) {
          float p = __expf(s4[f][j] - mnew);
          psum += p;
          split_bf16(p, ph[4 * f + j], pl[4 * f + j]);
        }
      psum += __shfl_xor(psum, 16);
      psum += __shfl_xor(psum, 32);
      l_run = l_run * alpha + psum;
      m_run = mnew;
      // ---- write P hi/lo to per-wave LDS (b64 per f) ----
#pragma unroll
      for (int f = 0; f < 2; ++f) {
        *(int2*)&Phi[wave][r][16 * f + 4 * g] = make_int2(
            (int)(unsigned short)ph[4 * f + 0] |
                ((int)(unsigned short)ph[4 * f + 1] << 16),
            (int)(unsigned short)ph[4 * f + 2] |
                ((int)(unsigned short)ph[4 * f + 3] << 16));
        *(int2*)&Plo[wave][r][16 * f + 4 * g] = make_int2(
            (int)(unsigned short)pl[4 * f + 0] |
                ((int)(unsigned short)pl[4 * f + 1] << 16),
            (int)(unsigned short)pl[4 * f + 2] |
                ((int)(unsigned short)pl[4 * f + 3] << 16));
      }
      // ---- rescale O by alpha of row (4g+j) ----
      float aj[4];
#pragma unroll
      for (int j = 0; j < 4; ++j) aj[j] = __shfl(alpha, 4 * g + j);
#pragma unroll
      for (int hf = 0; hf < 8; ++hf)
#pragma unroll
        for (int j = 0; j < 4; ++j) acc[hf][j] *= aj[j];
      // ---- O += P * V (A=P from LDS, B=Vt from LDS) ----
      short8v pa = *(const short8v*)&Phi[wave][r][8 * g];
      short8v pb = *(const short8v*)&Plo[wave][r][8 * g];
#pragma unroll
      for (int hf = 0; hf < 8; ++hf) {
        short8v va = *(const short8v*)&Vthi[16 * hf + r][8 * g];
        short8v vb = *(const short8v*)&Vtlo[16 * hf + r][8 * g];
        acc[hf] = MFMA16(pa, va, acc[hf]);
        acc[hf] = MFMA16(pa, vb, acc[hf]);
        acc[hf] = MFMA16(pb, va, acc[hf]);
      }
    }
  }
  // ---- epilogue: divide by l, store ----
  const float il = 1.f / l_run;
  float lj[4];
#pragma unroll
  for (int j = 0; j < 4; ++j) lj[j] = __shfl(il, 4 * g + j);
  float* Ob = O + ((size_t)b * NS + qw) * ND + h * HD;
#pragma unroll
  for (int hf = 0; hf < 8; ++hf)
#pragma unroll
    for (int j = 0; j < 4; ++j)
      Ob[(size_t)(4 * g + j) * ND + 16 * hf + r] = acc[hf][j] * lj[j];
}

// ---------------------------------------------------------------------------
// Launch: qkv+rope GEMM -> MFMA flash attention -> output GEMM.
// Workspace: qkv [B,S,3D] fp32 (96 MiB) + attn [B,S,D] fp32 (32 MiB).
// ---------------------------------------------------------------------------
extern "C" void kernel_launch(void* const* d_in, const int* in_sizes, int n_in,
                              void* d_out, int out_size, void* d_ws,
                              size_t ws_size, hipStream_t stream) {
  const float* x = (const float*)d_in[0];
  const float* Wqkv = (const float*)d_in[1];
  const float* Wo = (const float*)d_in[2];
  float* out = (float*)d_out;
  float* qkv = (float*)d_ws;                           // 25165824 floats
  float* attn = qkv + (size_t)NB * NS * 3 * ND;        // 8388608 floats

  gemm_f32_kernel<true><<<dim3(3 * ND / 128, NB * NS / 128), 256, 0, stream>>>(
      x, Wqkv, qkv, NB * NS, 3 * ND, ND);
  flash_attn_mfma<<<dim3(16, 32), 512, 0, stream>>>(qkv, attn);
  gemm_f32_kernel<false><<<dim3(ND / 128, NB * NS / 128), 256, 0, stream>>>(
      attn, Wo, out, NB * NS, ND, ND);
}

// Round 8
// 757.332 us; speedup vs baseline: 10.8435x; 2.3955x over previous
//
#include <hip/hip_runtime.h>
#include <cstddef>
#include <cstdint>
#include <math.h>

// Problem constants (B=2, S=2048, D=2048, H=16, hd=128)
#define NB 2
#define NS 2048
#define ND 2048
#define NH 16
#define HD 128

typedef __attribute__((ext_vector_type(8))) short short8v;   // 8 bf16 (4 VGPR)
typedef __attribute__((ext_vector_type(4))) float float4v;   // MFMA acc

#define MFMA16(A, B, C) __builtin_amdgcn_mfma_f32_16x16x32_bf16(A, B, C, 0, 0, 0)

// Split fp32 into bf16 hi + bf16 lo (x ~= hi + lo, rel err ~2^-17).
__device__ __forceinline__ void split_bf16(float x, short& hi, short& lo) {
  unsigned u = __float_as_uint(x);
  unsigned hb = (u + 0x7FFFu + ((u >> 16) & 1u)) >> 16;
  float hif = __uint_as_float(hb << 16);
  float r = x - hif;
  unsigned ul = __float_as_uint(r);
  hi = (short)hb;
  lo = (short)((ul + 0x7FFFu + ((ul >> 16) & 1u)) >> 16);
}

__device__ __forceinline__ int pack2(short a, short b) {
  return (int)(unsigned short)a | ((int)(unsigned short)b << 16);
}

// ---------------------------------------------------------------------------
// RoPE cos/sin table: tab[spos][p] = {cos, sin}, spos<2048, p<64. 1 MiB.
// ---------------------------------------------------------------------------
__global__ __launch_bounds__(256) void rope_table_kernel(float2* tab) {
  const int id = blockIdx.x * 256 + threadIdx.x;  // 131072 total
  const int spos = id >> 6, p = id & 63;
  const float invf = powf(10000.f, -(float)p * (1.f / 64.f));
  float s, c;
  sincosf((float)spos * invf, &s, &c);
  tab[id] = make_float2(c, s);
}

// ---------------------------------------------------------------------------
// Transpose + split: W[K][N] fp32 -> Th[N][K], Tl[N][K] bf16.
// ---------------------------------------------------------------------------
__global__ __launch_bounds__(256) void transpose_split_kernel(
    const float* __restrict__ W, short* __restrict__ Th, short* __restrict__ Tl,
    int K, int N) {
  __shared__ float T[32][33];
  const int tid = threadIdx.x;
  const int n0 = blockIdx.x * 32, k0 = blockIdx.y * 32;
  {
    const int r = tid >> 3, c4 = (tid & 7) << 2;
    float4 v = *(const float4*)&W[(size_t)(k0 + r) * N + n0 + c4];
    T[r][c4 + 0] = v.x;
    T[r][c4 + 1] = v.y;
    T[r][c4 + 2] = v.z;
    T[r][c4 + 3] = v.w;
  }
  __syncthreads();
  const int n = tid >> 3, k4 = (tid & 7) << 2;
  short h[4], l[4];
#pragma unroll
  for (int e = 0; e < 4; ++e) split_bf16(T[k4 + e][n], h[e], l[e]);
  const size_t off = (size_t)(n0 + n) * K + k0 + k4;
  *(int2*)&Th[off] = make_int2(pack2(h[0], h[1]), pack2(h[2], h[3]));
  *(int2*)&Tl[off] = make_int2(pack2(l[0], l[1]), pack2(l[2], l[3]));
}

// ---------------------------------------------------------------------------
// Split-bf16 MFMA GEMM: C[M,N] = A[M,K] (fp32) @ W (pre-split, BT[N][K] bf16
// hi/lo). 128x128 tile, BK=32, 256 thr = 4 waves (2x2), 4x4 16x16 frags/wave.
// C = Ah*Bh + Ah*Bl + Al*Bh (3 MFMA / product pair). A split inline at
// staging. LDS rows padded to 40 shorts (80 B) -> <=2-way bank alias.
// Optional RoPE epilogue (table-driven) for the QKV projection.
// ---------------------------------------------------------------------------
template <bool ROPE>
__global__ __launch_bounds__(256) void gemm_bf16x3_kernel(
    const float* __restrict__ A, const short* __restrict__ BTh,
    const short* __restrict__ BTl, float* __restrict__ C, int M, int N, int K,
    const float2* __restrict__ rope_tab) {
  __shared__ short Ah[128][40], Al[128][40];
  __shared__ short Bh[128][40], Bl[128][40];
  const int tid = threadIdx.x;
  const int wave = tid >> 6, lane = tid & 63;
  const int g = lane >> 4, r = lane & 15;
  const int wy = wave >> 1, wx = wave & 1;
  const int m0 = blockIdx.y * 128, n0 = blockIdx.x * 128;
  const int wm = wy * 64, wn = wx * 64;

  // staging maps
  const int ar = tid >> 1, ac = (tid & 1) << 4;   // A: row, col (16 fp32)
  const int br = tid >> 1, bc = (tid & 1) << 4;   // B: row, col (16 shorts)

  const float* aptr = A + (size_t)(m0 + ar) * K + ac;
  const short* bhp = BTh + (size_t)(n0 + br) * K + bc;
  const short* blp = BTl + (size_t)(n0 + br) * K + bc;

  float4v acc[4][4];
#pragma unroll
  for (int i = 0; i < 4; ++i)
#pragma unroll
    for (int j = 0; j < 4; ++j) acc[i][j] = (float4v){0.f, 0.f, 0.f, 0.f};

  // prologue: chunk 0 loads
  float4 a0 = *(const float4*)(aptr);
  float4 a1 = *(const float4*)(aptr + 4);
  float4 a2 = *(const float4*)(aptr + 8);
  float4 a3 = *(const float4*)(aptr + 12);
  int4 bh0 = *(const int4*)(bhp);
  int4 bh1 = *(const int4*)(bhp + 8);
  int4 bl0 = *(const int4*)(blp);
  int4 bl1 = *(const int4*)(blp + 8);

  for (int k0 = 0; k0 < K; k0 += 32) {
    __syncthreads();  // previous chunk consumed
    {                 // split A regs and write LDS
      float xs[16] = {a0.x, a0.y, a0.z, a0.w, a1.x, a1.y, a1.z, a1.w,
                      a2.x, a2.y, a2.z, a2.w, a3.x, a3.y, a3.z, a3.w};
      short h[16], l[16];
#pragma unroll
      for (int e = 0; e < 16; ++e) split_bf16(xs[e], h[e], l[e]);
      *(int4*)&Ah[ar][ac] =
          make_int4(pack2(h[0], h[1]), pack2(h[2], h[3]), pack2(h[4], h[5]),
                    pack2(h[6], h[7]));
      *(int4*)&Ah[ar][ac + 8] =
          make_int4(pack2(h[8], h[9]), pack2(h[10], h[11]),
                    pack2(h[12], h[13]), pack2(h[14], h[15]));
      *(int4*)&Al[ar][ac] =
          make_int4(pack2(l[0], l[1]), pack2(l[2], l[3]), pack2(l[4], l[5]),
                    pack2(l[6], l[7]));
      *(int4*)&Al[ar][ac + 8] =
          make_int4(pack2(l[8], l[9]), pack2(l[10], l[11]),
                    pack2(l[12], l[13]), pack2(l[14], l[15]));
      *(int4*)&Bh[br][bc] = bh0;
      *(int4*)&Bh[br][bc + 8] = bh1;
      *(int4*)&Bl[br][bc] = bl0;
      *(int4*)&Bl[br][bc + 8] = bl1;
    }
    __syncthreads();
    if (k0 + 32 < K) {  // prefetch next chunk
      const float* an = aptr + k0 + 32;
      a0 = *(const float4*)(an);
      a1 = *(const float4*)(an + 4);
      a2 = *(const float4*)(an + 8);
      a3 = *(const float4*)(an + 12);
      bh0 = *(const int4*)(bhp + k0 + 32);
      bh1 = *(const int4*)(bhp + k0 + 40);
      bl0 = *(const int4*)(blp + k0 + 32);
      bl1 = *(const int4*)(blp + k0 + 40);
    }
    // fragments + MFMA
    short8v afh[4], afl[4], bfh[4], bfl[4];
#pragma unroll
    for (int mi = 0; mi < 4; ++mi) {
      afh[mi] = *(const short8v*)&Ah[wm + mi * 16 + r][8 * g];
      afl[mi] = *(const short8v*)&Al[wm + mi * 16 + r][8 * g];
    }
#pragma unroll
    for (int nj = 0; nj < 4; ++nj) {
      bfh[nj] = *(const short8v*)&Bh[wn + nj * 16 + r][8 * g];
      bfl[nj] = *(const short8v*)&Bl[wn + nj * 16 + r][8 * g];
    }
#pragma unroll
    for (int mi = 0; mi < 4; ++mi)
#pragma unroll
      for (int nj = 0; nj < 4; ++nj) {
        acc[mi][nj] = MFMA16(afh[mi], bfh[nj], acc[mi][nj]);
        acc[mi][nj] = MFMA16(afh[mi], bfl[nj], acc[mi][nj]);
        acc[mi][nj] = MFMA16(afl[mi], bfh[nj], acc[mi][nj]);
      }
  }

  if (ROPE && n0 < 2 * ND) {  // q,k slabs only (v passthrough)
    int p[4];
#pragma unroll
    for (int nj = 0; nj < 4; ++nj)
      p[nj] = ((n0 + wn + nj * 16 + r) & (HD - 1)) >> 1;
    const bool even = (r & 1) == 0;
#pragma unroll
    for (int mi = 0; mi < 4; ++mi)
#pragma unroll
      for (int j = 0; j < 4; ++j) {
        const int spos = (m0 + wm + mi * 16 + 4 * g + j) & (NS - 1);
#pragma unroll
        for (int nj = 0; nj < 4; ++nj) {
          const float2 cs = rope_tab[spos * 64 + p[nj]];
          const float own = acc[mi][nj][j];
          const float oth = __shfl_xor(own, 1);
          acc[mi][nj][j] = even ? own * cs.x - oth * cs.y
                                : oth * cs.y + own * cs.x;
        }
      }
  }
#pragma unroll
  for (int mi = 0; mi < 4; ++mi)
#pragma unroll
    for (int j = 0; j < 4; ++j) {
      const size_t row = m0 + wm + mi * 16 + 4 * g + j;
      float* Crow = C + row * N + n0 + wn;
#pragma unroll
      for (int nj = 0; nj < 4; ++nj) Crow[nj * 16 + r] = acc[mi][nj][j];
    }
}

// ---------------------------------------------------------------------------
// Fallback tiled fp32 GEMM (validated round-5/6 kernel, unchanged).
// ---------------------------------------------------------------------------
template <bool ROPE>
__global__ __launch_bounds__(256) void gemm_f32_kernel(
    const float* __restrict__ A, const float* __restrict__ Bm,
    float* __restrict__ C, int M, int N, int K) {
  __shared__ float As[16][132];
  __shared__ float Bs[16][132];
  const int tid = threadIdx.x;
  const int m0 = blockIdx.y * 128;
  const int n0 = blockIdx.x * 128;
  const int tr = tid >> 4;
  const int tc = tid & 15;
  const int la_r = tid >> 1;
  const int la_c = (tid & 1) << 3;
  const int lb_r = tid >> 4;
  const int lb_c = (tid & 15) << 3;

  const float* Aptr = A + (size_t)(m0 + la_r) * K + la_c;
  const float* Bptr = Bm + (size_t)lb_r * N + n0 + lb_c;

  float acc[8][8] = {};

  float4 av0 = *(const float4*)(Aptr);
  float4 av1 = *(const float4*)(Aptr + 4);
  float4 bv0 = *(const float4*)(Bptr);
  float4 bv1 = *(const float4*)(Bptr + 4);

  for (int k0 = 0; k0 < K; k0 += 16) {
    __syncthreads();
    As[la_c + 0][la_r] = av0.x;
    As[la_c + 1][la_r] = av0.y;
    As[la_c + 2][la_r] = av0.z;
    As[la_c + 3][la_r] = av0.w;
    As[la_c + 4][la_r] = av1.x;
    As[la_c + 5][la_r] = av1.y;
    As[la_c + 6][la_r] = av1.z;
    As[la_c + 7][la_r] = av1.w;
    *(float4*)&Bs[lb_r][lb_c] = bv0;
    *(float4*)&Bs[lb_r][lb_c + 4] = bv1;
    __syncthreads();
    if (k0 + 16 < K) {
      const float* An = Aptr + k0 + 16;
      const float* Bn = Bptr + (size_t)(k0 + 16) * N;
      av0 = *(const float4*)(An);
      av1 = *(const float4*)(An + 4);
      bv0 = *(const float4*)(Bn);
      bv1 = *(const float4*)(Bn + 4);
    }
#pragma unroll
    for (int kk = 0; kk < 16; ++kk) {
      float a[8], b[8];
      *(float4*)&a[0] = *(const float4*)&As[kk][tr << 2];
      *(float4*)&a[4] = *(const float4*)&As[kk][64 + (tr << 2)];
      *(float4*)&b[0] = *(const float4*)&Bs[kk][tc << 2];
      *(float4*)&b[4] = *(const float4*)&Bs[kk][64 + (tc << 2)];
#pragma unroll
      for (int i = 0; i < 8; ++i)
#pragma unroll
        for (int j = 0; j < 8; ++j) acc[i][j] = fmaf(a[i], b[j], acc[i][j]);
    }
  }

  if (ROPE) {
    if ((n0 >> 11) < 2) {
#pragma unroll
      for (int g = 0; g < 2; ++g) {
        const int col = n0 + g * 64 + (tc << 2);
        const int d0 = col & (HD - 1);
        const int p0 = d0 >> 1;
        const float invf0 = powf(10000.f, -(float)p0 * (1.f / 64.f));
        const float invf1 = powf(10000.f, -(float)(p0 + 1) * (1.f / 64.f));
#pragma unroll
        for (int rg = 0; rg < 2; ++rg) {
#pragma unroll
          for (int i = 0; i < 4; ++i) {
            const int row = m0 + rg * 64 + (tr << 2) + i;
            const int spos = row & (NS - 1);
            float s0, c0, s1, c1;
            sincosf((float)spos * invf0, &s0, &c0);
            sincosf((float)spos * invf1, &s1, &c1);
            float* ar2 = &acc[rg * 4 + i][g * 4];
            const float xe0 = ar2[0], xo0 = ar2[1];
            const float xe1 = ar2[2], xo1 = ar2[3];
            ar2[0] = xe0 * c0 - xo0 * s0;
            ar2[1] = xe0 * s0 + xo0 * c0;
            ar2[2] = xe1 * c1 - xo1 * s1;
            ar2[3] = xe1 * s1 + xo1 * c1;
          }
        }
      }
    }
  }
#pragma unroll
  for (int rg = 0; rg < 2; ++rg) {
#pragma unroll
    for (int i = 0; i < 4; ++i) {
      const size_t row = m0 + rg * 64 + (tr << 2) + i;
      float* Crow = C + row * N + n0;
      float4 v0 = make_float4(acc[rg * 4 + i][0], acc[rg * 4 + i][1],
                              acc[rg * 4 + i][2], acc[rg * 4 + i][3]);
      float4 v1 = make_float4(acc[rg * 4 + i][4], acc[rg * 4 + i][5],
                              acc[rg * 4 + i][6], acc[rg * 4 + i][7]);
      *(float4*)(Crow + (tc << 2)) = v0;
      *(float4*)(Crow + 64 + (tc << 2)) = v1;
    }
  }
}

// ---------------------------------------------------------------------------
// Flash attention via split-bf16 MFMA (validated round-6 kernel, unchanged).
// ---------------------------------------------------------------------------
__global__ __launch_bounds__(512) void flash_attn_mfma(
    const float* __restrict__ qkv, float* __restrict__ O) {
  __shared__ short Khi[32][136];
  __shared__ short Klo[32][136];
  __shared__ short Vthi[128][40];
  __shared__ short Vtlo[128][40];
  __shared__ short Phi[8][16][40];
  __shared__ short Plo[8][16][40];

  const int tid = threadIdx.x;
  const int lane = tid & 63;
  const int wave = tid >> 6;
  const int g = lane >> 4;
  const int r = lane & 15;
  const int qtile = 15 - blockIdx.x;
  const int bh = blockIdx.y;
  const int b = bh >> 4, h = bh & 15;
  const int qb = qtile << 7;
  const int qw = qb + (wave << 4);
  const size_t row3d = 3 * ND;
  const float* base = qkv + (size_t)b * NS * row3d + (size_t)h * HD;
  const float* Kg = base + ND;
  const float* Vg = base + 2 * ND;

  const float scale = 0.088388347648318447f;
  const float* Qrow = base + (size_t)(qw + r) * row3d;
  short8v qhi[4], qlo[4];
#pragma unroll
  for (int hf = 0; hf < 4; ++hf) {
    const float* p = Qrow + 32 * hf + 8 * g;
    float4 x0 = *(const float4*)(p);
    float4 x1 = *(const float4*)(p + 4);
    float xs[8] = {x0.x, x0.y, x0.z, x0.w, x1.x, x1.y, x1.z, x1.w};
#pragma unroll
    for (int i = 0; i < 8; ++i) {
      short hi_, lo_;
      split_bf16(xs[i] * scale, hi_, lo_);
      qhi[hf][i] = hi_;
      qlo[hf][i] = lo_;
    }
  }

  float4v acc[8];
#pragma unroll
  for (int i = 0; i < 8; ++i) acc[i] = (float4v){0.f, 0.f, 0.f, 0.f};
  float m_run = -INFINITY;
  float l_run = 0.f;

  const int skv = tid >> 4;
  const int shd = (tid & 15) << 3;
  const int vkv = (tid & 15) << 1;
  const int vhd = (tid >> 4) << 2;
  const int ntiles = (qtile + 1) << 2;

  for (int t = 0; t < ntiles; ++t) {
    const int kvb = t << 5;
    __syncthreads();
    {
      const float* kr = Kg + (size_t)(kvb + skv) * row3d + shd;
#pragma unroll
      for (int u = 0; u < 2; ++u) {
        float4 v = *(const float4*)(kr + 4 * u);
        short h0, l0, h1, l1, h2, l2, h3, l3;
        split_bf16(v.x, h0, l0);
        split_bf16(v.y, h1, l1);
        split_bf16(v.z, h2, l2);
        split_bf16(v.w, h3, l3);
        *(int2*)&Khi[skv][shd + 4 * u] =
            make_int2(pack2(h0, h1), pack2(h2, h3));
        *(int2*)&Klo[skv][shd + 4 * u] =
            make_int2(pack2(l0, l1), pack2(l2, l3));
      }
    }
    {
      const float* v0p = Vg + (size_t)(kvb + vkv) * row3d + vhd;
      const float* v1p = v0p + row3d;
      float4 a0 = *(const float4*)(v0p);
      float4 b0 = *(const float4*)(v1p);
      float e0[4] = {a0.x, a0.y, a0.z, a0.w};
      float e1[4] = {b0.x, b0.y, b0.z, b0.w};
#pragma unroll
      for (int e = 0; e < 4; ++e) {
        short h0, l0, h1, l1;
        split_bf16(e0[e], h0, l0);
        split_bf16(e1[e], h1, l1);
        *(int*)&Vthi[vhd + e][vkv] = pack2(h0, h1);
        *(int*)&Vtlo[vhd + e][vkv] = pack2(l0, l1);
      }
    }
    __syncthreads();

    if (kvb <= qw + 15) {
      float4v s4[2];
#pragma unroll
      for (int f = 0; f < 2; ++f) s4[f] = (float4v){0.f, 0.f, 0.f, 0.f};
#pragma unroll
      for (int f = 0; f < 2; ++f) {
#pragma unroll
        for (int hf = 0; hf < 4; ++hf) {
          short8v ka = *(const short8v*)&Khi[16 * f + r][32 * hf + 8 * g];
          short8v kb = *(const short8v*)&Klo[16 * f + r][32 * hf + 8 * g];
          s4[f] = MFMA16(ka, qhi[hf], s4[f]);
          s4[f] = MFMA16(ka, qlo[hf], s4[f]);
          s4[f] = MFMA16(kb, qhi[hf], s4[f]);
        }
      }
      const int qglob = qw + r;
      if (kvb + 31 > qw) {
#pragma unroll
        for (int f = 0; f < 2; ++f)
#pragma unroll
          for (int j = 0; j < 4; ++j)
            if (kvb + 16 * f + 4 * g + j > qglob) s4[f][j] = -INFINITY;
      }
      float tmax = s4[0][0];
#pragma unroll
      for (int f = 0; f < 2; ++f)
#pragma unroll
        for (int j = 0; j < 4; ++j) tmax = fmaxf(tmax, s4[f][j]);
      tmax = fmaxf(tmax, __shfl_xor(tmax, 16));
      tmax = fmaxf(tmax, __shfl_xor(tmax, 32));
      const float mnew = fmaxf(m_run, tmax);
      const float alpha = __expf(m_run - mnew);
      float psum = 0.f;
      short ph[8], pl[8];
#pragma unroll
      for (int f = 0; f < 2; ++f)
#pragma unroll
        for (int j = 0; j < 4; ++j) {
          float p = __expf(s4[f][j] - mnew);
          psum += p;
          split_bf16(p, ph[4 * f + j], pl[4 * f + j]);
        }
      psum += __shfl_xor(psum, 16);
      psum += __shfl_xor(psum, 32);
      l_run = l_run * alpha + psum;
      m_run = mnew;
#pragma unroll
      for (int f = 0; f < 2; ++f) {
        *(int2*)&Phi[wave][r][16 * f + 4 * g] = make_int2(
            pack2(ph[4 * f + 0], ph[4 * f + 1]),
            pack2(ph[4 * f + 2], ph[4 * f + 3]));
        *(int2*)&Plo[wave][r][16 * f + 4 * g] = make_int2(
            pack2(pl[4 * f + 0], pl[4 * f + 1]),
            pack2(pl[4 * f + 2], pl[4 * f + 3]));
      }
      float aj[4];
#pragma unroll
      for (int j = 0; j < 4; ++j) aj[j] = __shfl(alpha, 4 * g + j);
#pragma unroll
      for (int hf = 0; hf < 8; ++hf)
#pragma unroll
        for (int j = 0; j < 4; ++j) acc[hf][j] *= aj[j];
      short8v pa = *(const short8v*)&Phi[wave][r][8 * g];
      short8v pb = *(const short8v*)&Plo[wave][r][8 * g];
#pragma unroll
      for (int hf = 0; hf < 8; ++hf) {
        short8v va = *(const short8v*)&Vthi[16 * hf + r][8 * g];
        short8v vb = *(const short8v*)&Vtlo[16 * hf + r][8 * g];
        acc[hf] = MFMA16(pa, va, acc[hf]);
        acc[hf] = MFMA16(pa, vb, acc[hf]);
        acc[hf] = MFMA16(pb, va, acc[hf]);
      }
    }
  }
  const float il = 1.f / l_run;
  float lj[4];
#pragma unroll
  for (int j = 0; j < 4; ++j) lj[j] = __shfl(il, 4 * g + j);
  float* Ob = O + ((size_t)b * NS + qw) * ND + h * HD;
#pragma unroll
  for (int hf = 0; hf < 8; ++hf)
#pragma unroll
    for (int j = 0; j < 4; ++j)
      Ob[(size_t)(4 * g + j) * ND + 16 * hf + r] = acc[hf][j] * lj[j];
}

// ---------------------------------------------------------------------------
// Launch. Workspace (MFMA path, ~193 MiB):
//   qkv [B,S,3D] f32 | attn [B,S,D] f32 | WqkvT hi/lo bf16 | WoT hi/lo bf16
//   | rope table. Falls back to fp32 GEMMs if ws_size is too small.
// ---------------------------------------------------------------------------
extern "C" void kernel_launch(void* const* d_in, const int* in_sizes, int n_in,
                              void* d_out, int out_size, void* d_ws,
                              size_t ws_size, hipStream_t stream) {
  const float* x = (const float*)d_in[0];
  const float* Wqkv = (const float*)d_in[1];
  const float* Wo = (const float*)d_in[2];
  float* out = (float*)d_out;
  float* qkv = (float*)d_ws;                       // 25165824 f
  float* attn = qkv + (size_t)NB * NS * 3 * ND;    // 8388608 f
  short* wqh = (short*)(attn + (size_t)NB * NS * ND);  // 12582912 s each
  short* wql = wqh + (size_t)ND * 3 * ND;
  short* woh = wql + (size_t)ND * 3 * ND;          // 4194304 s each
  short* wol = woh + (size_t)ND * ND;
  float2* tab = (float2*)(wol + (size_t)ND * ND);  // 131072 float2

  const size_t needed =
      ((size_t)NB * NS * 3 * ND + (size_t)NB * NS * ND) * 4 +
      ((size_t)ND * 3 * ND + (size_t)ND * ND) * 2 * 2 + (size_t)NS * 64 * 8;

  if (ws_size >= needed) {
    rope_table_kernel<<<NS * 64 / 256, 256, 0, stream>>>(tab);
    transpose_split_kernel<<<dim3(3 * ND / 32, ND / 32), 256, 0, stream>>>(
        Wqkv, wqh, wql, ND, 3 * ND);
    transpose_split_kernel<<<dim3(ND / 32, ND / 32), 256, 0, stream>>>(
        Wo, woh, wol, ND, ND);
    gemm_bf16x3_kernel<true>
        <<<dim3(3 * ND / 128, NB * NS / 128), 256, 0, stream>>>(
            x, wqh, wql, qkv, NB * NS, 3 * ND, ND, tab);
    flash_attn_mfma<<<dim3(16, 32), 512, 0, stream>>>(qkv, attn);
    gemm_bf16x3_kernel<false>
        <<<dim3(ND / 128, NB * NS / 128), 256, 0, stream>>>(
            attn, woh, wol, out, NB * NS, ND, ND, tab);
  } else {
    gemm_f32_kernel<true>
        <<<dim3(3 * ND / 128, NB * NS / 128), 256, 0, stream>>>(
            x, Wqkv, qkv, NB * NS, 3 * ND, ND);
    flash_attn_mfma<<<dim3(16, 32), 512, 0, stream>>>(qkv, attn);
    gemm_f32_kernel<false>
        <<<dim3(ND / 128, NB * NS / 128), 256, 0, stream>>>(
            attn, Wo, out, NB * NS, ND, ND);
  }
}

// Round 10
// 754.744 us; speedup vs baseline: 10.8807x; 1.0034x over previous
//
#include <hip/hip_runtime.h>
#include <cstddef>
#include <cstdint>
#include <math.h>

// Problem constants (B=2, S=2048, D=2048, H=16, hd=128)
#define NB 2
#define NS 2048
#define ND 2048
#define NH 16
#define HD 128

typedef __attribute__((ext_vector_type(8))) short short8v;   // 8 bf16 (4 VGPR)
typedef __attribute__((ext_vector_type(4))) float float4v;   // MFMA acc

#define MFMA16(A, B, C) __builtin_amdgcn_mfma_f32_16x16x32_bf16(A, B, C, 0, 0, 0)

// Split fp32 into bf16 hi + bf16 lo (x ~= hi + lo, rel err ~2^-17).
__device__ __forceinline__ void split_bf16(float x, short& hi, short& lo) {
  unsigned u = __float_as_uint(x);
  unsigned hb = (u + 0x7FFFu + ((u >> 16) & 1u)) >> 16;
  float hif = __uint_as_float(hb << 16);
  float r = x - hif;
  unsigned ul = __float_as_uint(r);
  hi = (short)hb;
  lo = (short)((ul + 0x7FFFu + ((ul >> 16) & 1u)) >> 16);
}

__device__ __forceinline__ int pack2(short a, short b) {
  return (int)(unsigned short)a | ((int)(unsigned short)b << 16);
}

// ---------------------------------------------------------------------------
// RoPE cos/sin table: tab[spos][p] = {cos, sin}, spos<2048, p<64. 1 MiB.
// ---------------------------------------------------------------------------
__global__ __launch_bounds__(256) void rope_table_kernel(float2* tab) {
  const int id = blockIdx.x * 256 + threadIdx.x;  // 131072 total
  const int spos = id >> 6, p = id & 63;
  const float invf = powf(10000.f, -(float)p * (1.f / 64.f));
  float s, c;
  sincosf((float)spos * invf, &s, &c);
  tab[id] = make_float2(c, s);
}

// ---------------------------------------------------------------------------
// Elementwise split: in[n4*4] fp32 -> hi, lo bf16 arrays (same layout).
// ---------------------------------------------------------------------------
__global__ __launch_bounds__(256) void split_kernel(
    const float* __restrict__ in, short* __restrict__ hi,
    short* __restrict__ lo, int n4) {
  for (int i = blockIdx.x * 256 + threadIdx.x; i < n4;
       i += gridDim.x * 256) {
    float4 v = ((const float4*)in)[i];
    short h0, l0, h1, l1, h2, l2, h3, l3;
    split_bf16(v.x, h0, l0);
    split_bf16(v.y, h1, l1);
    split_bf16(v.z, h2, l2);
    split_bf16(v.w, h3, l3);
    ((int2*)hi)[i] = make_int2(pack2(h0, h1), pack2(h2, h3));
    ((int2*)lo)[i] = make_int2(pack2(l0, l1), pack2(l2, l3));
  }
}

// ---------------------------------------------------------------------------
// Transpose + split: W[K][N] fp32 -> Th[N][K], Tl[N][K] bf16.
// ---------------------------------------------------------------------------
__global__ __launch_bounds__(256) void transpose_split_kernel(
    const float* __restrict__ W, short* __restrict__ Th, short* __restrict__ Tl,
    int K, int N) {
  __shared__ float T[32][33];
  const int tid = threadIdx.x;
  const int n0 = blockIdx.x * 32, k0 = blockIdx.y * 32;
  {
    const int r = tid >> 3, c4 = (tid & 7) << 2;
    float4 v = *(const float4*)&W[(size_t)(k0 + r) * N + n0 + c4];
    T[r][c4 + 0] = v.x;
    T[r][c4 + 1] = v.y;
    T[r][c4 + 2] = v.z;
    T[r][c4 + 3] = v.w;
  }
  __syncthreads();
  const int n = tid >> 3, k4 = (tid & 7) << 2;
  short h[4], l[4];
#pragma unroll
  for (int e = 0; e < 4; ++e) split_bf16(T[k4 + e][n], h[e], l[e]);
  const size_t off = (size_t)(n0 + n) * K + k0 + k4;
  *(int2*)&Th[off] = make_int2(pack2(h[0], h[1]), pack2(h[2], h[3]));
  *(int2*)&Tl[off] = make_int2(pack2(l[0], l[1]), pack2(l[2], l[3]));
}

// ---------------------------------------------------------------------------
// Split-bf16 MFMA GEMM: C[M,N] = A[M,K] @ W (pre-split BT[N][K] bf16 hi/lo).
// 128x128 tile, BK=32, 256 thr = 4 waves (2x2), 4x4 16x16 frags/wave.
// C = Ah*Bh + Ah*Bl + Al*Bh. ASPLIT: A pre-split to bf16 hi/lo in global
// (pure int4 staging); else A fp32, split inline (round-8 validated path).
// CHX>0: bijective XCD 2D-chunk swizzle (8 XCDs as 4x2, chunks CHX x CHY).
// LDS rows padded to 40 shorts -> <=2-way bank alias. Optional RoPE epilogue.
// ---------------------------------------------------------------------------
template <bool ROPE, bool ASPLIT, int CHX, int CHY>
__global__ __launch_bounds__(256) void gemm_bf16x3_kernel(
    const float* __restrict__ Af, const short* __restrict__ Ahg,
    const short* __restrict__ Alg, const short* __restrict__ BTh,
    const short* __restrict__ BTl, float* __restrict__ C, int M, int N, int K,
    const float2* __restrict__ rope_tab) {
  __shared__ short Ah[128][40], Al[128][40];
  __shared__ short Bh[128][40], Bl[128][40];
  const int tid = threadIdx.x;
  const int wave = tid >> 6, lane = tid & 63;
  const int g = lane >> 4, r = lane & 15;
  const int wy = wave >> 1, wx = wave & 1;

  int bx = blockIdx.x, by = blockIdx.y;
  if (CHX > 0) {  // XCD-aware 2D chunk swizzle (bijective)
    const int flat = by * gridDim.x + bx;
    const int xcd = flat & 7, idx = flat >> 3;
    bx = (xcd & 3) * CHX + idx % CHX;
    by = (xcd >> 2) * CHY + idx / CHX;
  }
  const int m0 = by * 128, n0 = bx * 128;
  const int wm = wy * 64, wn = wx * 64;

  // staging maps: 2 threads per row, 16 elements each
  const int ar = tid >> 1, ac = (tid & 1) << 4;

  const short* bhp = BTh + (size_t)(n0 + ar) * K + ac;
  const short* blp = BTl + (size_t)(n0 + ar) * K + ac;

  float4v acc[4][4];
#pragma unroll
  for (int i = 0; i < 4; ++i)
#pragma unroll
    for (int j = 0; j < 4; ++j) acc[i][j] = (float4v){0.f, 0.f, 0.f, 0.f};

  // prologue: chunk 0 loads
  float4 a0, a1, a2, a3;
  int4 ah0, ah1, al0, al1;
  const float* aptr = nullptr;
  const short* ahp = nullptr;
  const short* alp = nullptr;
  if (ASPLIT) {
    ahp = Ahg + (size_t)(m0 + ar) * K + ac;
    alp = Alg + (size_t)(m0 + ar) * K + ac;
    ah0 = *(const int4*)(ahp);
    ah1 = *(const int4*)(ahp + 8);
    al0 = *(const int4*)(alp);
    al1 = *(const int4*)(alp + 8);
  } else {
    aptr = Af + (size_t)(m0 + ar) * K + ac;
    a0 = *(const float4*)(aptr);
    a1 = *(const float4*)(aptr + 4);
    a2 = *(const float4*)(aptr + 8);
    a3 = *(const float4*)(aptr + 12);
  }
  int4 bh0 = *(const int4*)(bhp);
  int4 bh1 = *(const int4*)(bhp + 8);
  int4 bl0 = *(const int4*)(blp);
  int4 bl1 = *(const int4*)(blp + 8);

  for (int k0 = 0; k0 < K; k0 += 32) {
    __syncthreads();  // previous chunk consumed
    if (ASPLIT) {
      *(int4*)&Ah[ar][ac] = ah0;
      *(int4*)&Ah[ar][ac + 8] = ah1;
      *(int4*)&Al[ar][ac] = al0;
      *(int4*)&Al[ar][ac + 8] = al1;
    } else {
      float xs[16] = {a0.x, a0.y, a0.z, a0.w, a1.x, a1.y, a1.z, a1.w,
                      a2.x, a2.y, a2.z, a2.w, a3.x, a3.y, a3.z, a3.w};
      short h[16], l[16];
#pragma unroll
      for (int e = 0; e < 16; ++e) split_bf16(xs[e], h[e], l[e]);
      *(int4*)&Ah[ar][ac] =
          make_int4(pack2(h[0], h[1]), pack2(h[2], h[3]), pack2(h[4], h[5]),
                    pack2(h[6], h[7]));
      *(int4*)&Ah[ar][ac + 8] =
          make_int4(pack2(h[8], h[9]), pack2(h[10], h[11]),
                    pack2(h[12], h[13]), pack2(h[14], h[15]));
      *(int4*)&Al[ar][ac] =
          make_int4(pack2(l[0], l[1]), pack2(l[2], l[3]), pack2(l[4], l[5]),
                    pack2(l[6], l[7]));
      *(int4*)&Al[ar][ac + 8] =
          make_int4(pack2(l[8], l[9]), pack2(l[10], l[11]),
                    pack2(l[12], l[13]), pack2(l[14], l[15]));
    }
    *(int4*)&Bh[ar][ac] = bh0;
    *(int4*)&Bh[ar][ac + 8] = bh1;
    *(int4*)&Bl[ar][ac] = bl0;
    *(int4*)&Bl[ar][ac + 8] = bl1;
    __syncthreads();
    if (k0 + 32 < K) {  // prefetch next chunk
      if (ASPLIT) {
        ah0 = *(const int4*)(ahp + k0 + 32);
        ah1 = *(const int4*)(ahp + k0 + 40);
        al0 = *(const int4*)(alp + k0 + 32);
        al1 = *(const int4*)(alp + k0 + 40);
      } else {
        const float* an = aptr + k0 + 32;
        a0 = *(const float4*)(an);
        a1 = *(const float4*)(an + 4);
        a2 = *(const float4*)(an + 8);
        a3 = *(const float4*)(an + 12);
      }
      bh0 = *(const int4*)(bhp + k0 + 32);
      bh1 = *(const int4*)(bhp + k0 + 40);
      bl0 = *(const int4*)(blp + k0 + 32);
      bl1 = *(const int4*)(blp + k0 + 40);
    }
    // fragments + MFMA
    short8v afh[4], afl[4], bfh[4], bfl[4];
#pragma unroll
    for (int mi = 0; mi < 4; ++mi) {
      afh[mi] = *(const short8v*)&Ah[wm + mi * 16 + r][8 * g];
      afl[mi] = *(const short8v*)&Al[wm + mi * 16 + r][8 * g];
    }
#pragma unroll
    for (int nj = 0; nj < 4; ++nj) {
      bfh[nj] = *(const short8v*)&Bh[wn + nj * 16 + r][8 * g];
      bfl[nj] = *(const short8v*)&Bl[wn + nj * 16 + r][8 * g];
    }
#pragma unroll
    for (int mi = 0; mi < 4; ++mi)
#pragma unroll
      for (int nj = 0; nj < 4; ++nj) {
        acc[mi][nj] = MFMA16(afh[mi], bfh[nj], acc[mi][nj]);
        acc[mi][nj] = MFMA16(afh[mi], bfl[nj], acc[mi][nj]);
        acc[mi][nj] = MFMA16(afl[mi], bfh[nj], acc[mi][nj]);
      }
  }

  if (ROPE && n0 < 2 * ND) {  // q,k slabs only (v passthrough)
    int p[4];
#pragma unroll
    for (int nj = 0; nj < 4; ++nj)
      p[nj] = ((n0 + wn + nj * 16 + r) & (HD - 1)) >> 1;
    const bool even = (r & 1) == 0;
#pragma unroll
    for (int mi = 0; mi < 4; ++mi)
#pragma unroll
      for (int j = 0; j < 4; ++j) {
        const int spos = (m0 + wm + mi * 16 + 4 * g + j) & (NS - 1);
#pragma unroll
        for (int nj = 0; nj < 4; ++nj) {
          const float2 cs = rope_tab[spos * 64 + p[nj]];
          const float own = acc[mi][nj][j];
          const float oth = __shfl_xor(own, 1);
          acc[mi][nj][j] = even ? own * cs.x - oth * cs.y
                                : oth * cs.y + own * cs.x;
        }
      }
  }
#pragma unroll
  for (int mi = 0; mi < 4; ++mi)
#pragma unroll
    for (int j = 0; j < 4; ++j) {
      const size_t row = m0 + wm + mi * 16 + 4 * g + j;
      float* Crow = C + row * N + n0 + wn;
#pragma unroll
      for (int nj = 0; nj < 4; ++nj) Crow[nj * 16 + r] = acc[mi][nj][j];
    }
}

// ---------------------------------------------------------------------------
// Fallback tiled fp32 GEMM (validated round-5/6 kernel, unchanged).
// ---------------------------------------------------------------------------
template <bool ROPE>
__global__ __launch_bounds__(256) void gemm_f32_kernel(
    const float* __restrict__ A, const float* __restrict__ Bm,
    float* __restrict__ C, int M, int N, int K) {
  __shared__ float As[16][132];
  __shared__ float Bs[16][132];
  const int tid = threadIdx.x;
  const int m0 = blockIdx.y * 128;
  const int n0 = blockIdx.x * 128;
  const int tr = tid >> 4;
  const int tc = tid & 15;
  const int la_r = tid >> 1;
  const int la_c = (tid & 1) << 3;
  const int lb_r = tid >> 4;
  const int lb_c = (tid & 15) << 3;

  const float* Aptr = A + (size_t)(m0 + la_r) * K + la_c;
  const float* Bptr = Bm + (size_t)lb_r * N + n0 + lb_c;

  float acc[8][8] = {};

  float4 av0 = *(const float4*)(Aptr);
  float4 av1 = *(const float4*)(Aptr + 4);
  float4 bv0 = *(const float4*)(Bptr);
  float4 bv1 = *(const float4*)(Bptr + 4);

  for (int k0 = 0; k0 < K; k0 += 16) {
    __syncthreads();
    As[la_c + 0][la_r] = av0.x;
    As[la_c + 1][la_r] = av0.y;
    As[la_c + 2][la_r] = av0.z;
    As[la_c + 3][la_r] = av0.w;
    As[la_c + 4][la_r] = av1.x;
    As[la_c + 5][la_r] = av1.y;
    As[la_c + 6][la_r] = av1.z;
    As[la_c + 7][la_r] = av1.w;
    *(float4*)&Bs[lb_r][lb_c] = bv0;
    *(float4*)&Bs[lb_r][lb_c + 4] = bv1;
    __syncthreads();
    if (k0 + 16 < K) {
      const float* An = Aptr + k0 + 16;
      const float* Bn = Bptr + (size_t)(k0 + 16) * N;
      av0 = *(const float4*)(An);
      av1 = *(const float4*)(An + 4);
      bv0 = *(const float4*)(Bn);
      bv1 = *(const float4*)(Bn + 4);
    }
#pragma unroll
    for (int kk = 0; kk < 16; ++kk) {
      float a[8], b[8];
      *(float4*)&a[0] = *(const float4*)&As[kk][tr << 2];
      *(float4*)&a[4] = *(const float4*)&As[kk][64 + (tr << 2)];
      *(float4*)&b[0] = *(const float4*)&Bs[kk][tc << 2];
      *(float4*)&b[4] = *(const float4*)&Bs[kk][64 + (tc << 2)];
#pragma unroll
      for (int i = 0; i < 8; ++i)
#pragma unroll
        for (int j = 0; j < 8; ++j) acc[i][j] = fmaf(a[i], b[j], acc[i][j]);
    }
  }

  if (ROPE) {
    if ((n0 >> 11) < 2) {
#pragma unroll
      for (int g = 0; g < 2; ++g) {
        const int col = n0 + g * 64 + (tc << 2);
        const int d0 = col & (HD - 1);
        const int p0 = d0 >> 1;
        const float invf0 = powf(10000.f, -(float)p0 * (1.f / 64.f));
        const float invf1 = powf(10000.f, -(float)(p0 + 1) * (1.f / 64.f));
#pragma unroll
        for (int rg = 0; rg < 2; ++rg) {
#pragma unroll
          for (int i = 0; i < 4; ++i) {
            const int row = m0 + rg * 64 + (tr << 2) + i;
            const int spos = row & (NS - 1);
            float s0, c0, s1, c1;
            sincosf((float)spos * invf0, &s0, &c0);
            sincosf((float)spos * invf1, &s1, &c1);
            float* ar2 = &acc[rg * 4 + i][g * 4];
            const float xe0 = ar2[0], xo0 = ar2[1];
            const float xe1 = ar2[2], xo1 = ar2[3];
            ar2[0] = xe0 * c0 - xo0 * s0;
            ar2[1] = xe0 * s0 + xo0 * c0;
            ar2[2] = xe1 * c1 - xo1 * s1;
            ar2[3] = xe1 * s1 + xo1 * c1;
          }
        }
      }
    }
  }
#pragma unroll
  for (int rg = 0; rg < 2; ++rg) {
#pragma unroll
    for (int i = 0; i < 4; ++i) {
      const size_t row = m0 + rg * 64 + (tr << 2) + i;
      float* Crow = C + row * N + n0;
      float4 v0 = make_float4(acc[rg * 4 + i][0], acc[rg * 4 + i][1],
                              acc[rg * 4 + i][2], acc[rg * 4 + i][3]);
      float4 v1 = make_float4(acc[rg * 4 + i][4], acc[rg * 4 + i][5],
                              acc[rg * 4 + i][6], acc[rg * 4 + i][7]);
      *(float4*)(Crow + (tc << 2)) = v0;
      *(float4*)(Crow + 64 + (tc << 2)) = v1;
    }
  }
}

// ---------------------------------------------------------------------------
// Flash attention via split-bf16 MFMA (validated round-6 kernel, unchanged).
// ---------------------------------------------------------------------------
__global__ __launch_bounds__(512) void flash_attn_mfma(
    const float* __restrict__ qkv, float* __restrict__ O) {
  __shared__ short Khi[32][136];
  __shared__ short Klo[32][136];
  __shared__ short Vthi[128][40];
  __shared__ short Vtlo[128][40];
  __shared__ short Phi[8][16][40];
  __shared__ short Plo[8][16][40];

  const int tid = threadIdx.x;
  const int lane = tid & 63;
  const int wave = tid >> 6;
  const int g = lane >> 4;
  const int r = lane & 15;
  const int qtile = 15 - blockIdx.x;
  const int bh = blockIdx.y;
  const int b = bh >> 4, h = bh & 15;
  const int qb = qtile << 7;
  const int qw = qb + (wave << 4);
  const size_t row3d = 3 * ND;
  const float* base = qkv + (size_t)b * NS * row3d + (size_t)h * HD;
  const float* Kg = base + ND;
  const float* Vg = base + 2 * ND;

  const float scale = 0.088388347648318447f;
  const float* Qrow = base + (size_t)(qw + r) * row3d;
  short8v qhi[4], qlo[4];
#pragma unroll
  for (int hf = 0; hf < 4; ++hf) {
    const float* p = Qrow + 32 * hf + 8 * g;
    float4 x0 = *(const float4*)(p);
    float4 x1 = *(const float4*)(p + 4);
    float xs[8] = {x0.x, x0.y, x0.z, x0.w, x1.x, x1.y, x1.z, x1.w};
#pragma unroll
    for (int i = 0; i < 8; ++i) {
      short hi_, lo_;
      split_bf16(xs[i] * scale, hi_, lo_);
      qhi[hf][i] = hi_;
      qlo[hf][i] = lo_;
    }
  }

  float4v acc[8];
#pragma unroll
  for (int i = 0; i < 8; ++i) acc[i] = (float4v){0.f, 0.f, 0.f, 0.f};
  float m_run = -INFINITY;
  float l_run = 0.f;

  const int skv = tid >> 4;
  const int shd = (tid & 15) << 3;
  const int vkv = (tid & 15) << 1;
  const int vhd = (tid >> 4) << 2;
  const int ntiles = (qtile + 1) << 2;

  for (int t = 0; t < ntiles; ++t) {
    const int kvb = t << 5;
    __syncthreads();
    {
      const float* kr = Kg + (size_t)(kvb + skv) * row3d + shd;
#pragma unroll
      for (int u = 0; u < 2; ++u) {
        float4 v = *(const float4*)(kr + 4 * u);
        short h0, l0, h1, l1, h2, l2, h3, l3;
        split_bf16(v.x, h0, l0);
        split_bf16(v.y, h1, l1);
        split_bf16(v.z, h2, l2);
        split_bf16(v.w, h3, l3);
        *(int2*)&Khi[skv][shd + 4 * u] =
            make_int2(pack2(h0, h1), pack2(h2, h3));
        *(int2*)&Klo[skv][shd + 4 * u] =
            make_int2(pack2(l0, l1), pack2(l2, l3));
      }
    }
    {
      const float* v0p = Vg + (size_t)(kvb + vkv) * row3d + vhd;
      const float* v1p = v0p + row3d;
      float4 a0 = *(const float4*)(v0p);
      float4 b0 = *(const float4*)(v1p);
      float e0[4] = {a0.x, a0.y, a0.z, a0.w};
      float e1[4] = {b0.x, b0.y, b0.z, b0.w};
#pragma unroll
      for (int e = 0; e < 4; ++e) {
        short h0, l0, h1, l1;
        split_bf16(e0[e], h0, l0);
        split_bf16(e1[e], h1, l1);
        *(int*)&Vthi[vhd + e][vkv] = pack2(h0, h1);
        *(int*)&Vtlo[vhd + e][vkv] = pack2(l0, l1);
      }
    }
    __syncthreads();

    if (kvb <= qw + 15) {
      float4v s4[2];
#pragma unroll
      for (int f = 0; f < 2; ++f) s4[f] = (float4v){0.f, 0.f, 0.f, 0.f};
#pragma unroll
      for (int f = 0; f < 2; ++f) {
#pragma unroll
        for (int hf = 0; hf < 4; ++hf) {
          short8v ka = *(const short8v*)&Khi[16 * f + r][32 * hf + 8 * g];
          short8v kb = *(const short8v*)&Klo[16 * f + r][32 * hf + 8 * g];
          s4[f] = MFMA16(ka, qhi[hf], s4[f]);
          s4[f] = MFMA16(ka, qlo[hf], s4[f]);
          s4[f] = MFMA16(kb, qhi[hf], s4[f]);
        }
      }
      const int qglob = qw + r;
      if (kvb + 31 > qw) {
#pragma unroll
        for (int f = 0; f < 2; ++f)
#pragma unroll
          for (int j = 0; j < 4; ++j)
            if (kvb + 16 * f + 4 * g + j > qglob) s4[f][j] = -INFINITY;
      }
      float tmax = s4[0][0];
#pragma unroll
      for (int f = 0; f < 2; ++f)
#pragma unroll
        for (int j = 0; j < 4; ++j) tmax = fmaxf(tmax, s4[f][j]);
      tmax = fmaxf(tmax, __shfl_xor(tmax, 16));
      tmax = fmaxf(tmax, __shfl_xor(tmax, 32));
      const float mnew = fmaxf(m_run, tmax);
      const float alpha = __expf(m_run - mnew);
      float psum = 0.f;
      short ph[8], pl[8];
#pragma unroll
      for (int f = 0; f < 2; ++f)
#pragma unroll
        for (int j = 0; j < 4; ++j) {
          float p = __expf(s4[f][j] - mnew);
          psum += p;
          split_bf16(p, ph[4 * f + j], pl[4 * f + j]);
        }
      psum += __shfl_xor(psum, 16);
      psum += __shfl_xor(psum, 32);
      l_run = l_run * alpha + psum;
      m_run = mnew;
#pragma unroll
      for (int f = 0; f < 2; ++f) {
        *(int2*)&Phi[wave][r][16 * f + 4 * g] = make_int2(
            pack2(ph[4 * f + 0], ph[4 * f + 1]),
            pack2(ph[4 * f + 2], ph[4 * f + 3]));
        *(int2*)&Plo[wave][r][16 * f + 4 * g] = make_int2(
            pack2(pl[4 * f + 0], pl[4 * f + 1]),
            pack2(pl[4 * f + 2], pl[4 * f + 3]));
      }
      float aj[4];
#pragma unroll
      for (int j = 0; j < 4; ++j) aj[j] = __shfl(alpha, 4 * g + j);
#pragma unroll
      for (int hf = 0; hf < 8; ++hf)
#pragma unroll
        for (int j = 0; j < 4; ++j) acc[hf][j] *= aj[j];
      short8v pa = *(const short8v*)&Phi[wave][r][8 * g];
      short8v pb = *(const short8v*)&Plo[wave][r][8 * g];
#pragma unroll
      for (int hf = 0; hf < 8; ++hf) {
        short8v va = *(const short8v*)&Vthi[16 * hf + r][8 * g];
        short8v vb = *(const short8v*)&Vtlo[16 * hf + r][8 * g];
        acc[hf] = MFMA16(pa, va, acc[hf]);
        acc[hf] = MFMA16(pa, vb, acc[hf]);
        acc[hf] = MFMA16(pb, va, acc[hf]);
      }
    }
  }
  const float il = 1.f / l_run;
  float lj[4];
#pragma unroll
  for (int j = 0; j < 4; ++j) lj[j] = __shfl(il, 4 * g + j);
  float* Ob = O + ((size_t)b * NS + qw) * ND + h * HD;
#pragma unroll
  for (int hf = 0; hf < 8; ++hf)
#pragma unroll
    for (int j = 0; j < 4; ++j)
      Ob[(size_t)(4 * g + j) * ND + 16 * hf + r] = acc[hf][j] * lj[j];
}

// ---------------------------------------------------------------------------
// Launch. New layout (~257 MiB): qkv f32 | attn f32 | WqkvT hi/lo | WoT hi/lo
// | rope tab | xh/xl | ath/atl. Layered fallback: round-8 layout (202 MiB,
// inline-split A) -> fp32 GEMMs.
// ---------------------------------------------------------------------------
extern "C" void kernel_launch(void* const* d_in, const int* in_sizes, int n_in,
                              void* d_out, int out_size, void* d_ws,
                              size_t ws_size, hipStream_t stream) {
  const float* x = (const float*)d_in[0];
  const float* Wqkv = (const float*)d_in[1];
  const float* Wo = (const float*)d_in[2];
  float* out = (float*)d_out;
  float* qkv = (float*)d_ws;                       // 25165824 f
  float* attn = qkv + (size_t)NB * NS * 3 * ND;    // 8388608 f
  short* wqh = (short*)(attn + (size_t)NB * NS * ND);  // 12582912 s each
  short* wql = wqh + (size_t)ND * 3 * ND;
  short* woh = wql + (size_t)ND * 3 * ND;          // 4194304 s each
  short* wol = woh + (size_t)ND * ND;
  float2* tab = (float2*)(wol + (size_t)ND * ND);  // 131072 float2
  short* xh = (short*)(tab + (size_t)NS * 64);     // 8388608 s each
  short* xl = xh + (size_t)NB * NS * ND;
  short* ath = xl + (size_t)NB * NS * ND;
  short* atl = ath + (size_t)NB * NS * ND;

  const size_t base_need =
      ((size_t)NB * NS * 3 * ND + (size_t)NB * NS * ND) * 4 +
      ((size_t)ND * 3 * ND + (size_t)ND * ND) * 2 * 2 + (size_t)NS * 64 * 8;
  const size_t full_need = base_need + (size_t)NB * NS * ND * 2 * 4;

  const int M = NB * NS;
  if (ws_size >= base_need) {
    rope_table_kernel<<<NS * 64 / 256, 256, 0, stream>>>(tab);
    transpose_split_kernel<<<dim3(3 * ND / 32, ND / 32), 256, 0, stream>>>(
        Wqkv, wqh, wql, ND, 3 * ND);
    transpose_split_kernel<<<dim3(ND / 32, ND / 32), 256, 0, stream>>>(
        Wo, woh, wol, ND, ND);
    if (ws_size >= full_need) {
      split_kernel<<<2048, 256, 0, stream>>>(x, xh, xl, M * ND / 4);
      gemm_bf16x3_kernel<true, true, 12, 16>
          <<<dim3(3 * ND / 128, M / 128), 256, 0, stream>>>(
              nullptr, xh, xl, wqh, wql, qkv, M, 3 * ND, ND, tab);
      flash_attn_mfma<<<dim3(16, 32), 512, 0, stream>>>(qkv, attn);
      split_kernel<<<2048, 256, 0, stream>>>(attn, ath, atl, M * ND / 4);
      gemm_bf16x3_kernel<false, true, 4, 16>
          <<<dim3(ND / 128, M / 128), 256, 0, stream>>>(
              nullptr, ath, atl, woh, wol, out, M, ND, ND, tab);
    } else {
      gemm_bf16x3_kernel<true, false, 0, 0>
          <<<dim3(3 * ND / 128, M / 128), 256, 0, stream>>>(
              x, nullptr, nullptr, wqh, wql, qkv, M, 3 * ND, ND, tab);
      flash_attn_mfma<<<dim3(16, 32), 512, 0, stream>>>(qkv, attn);
      gemm_bf16x3_kernel<false, false, 0, 0>
          <<<dim3(ND / 128, M / 128), 256, 0, stream>>>(
              attn, nullptr, nullptr, woh, wol, out, M, ND, ND, tab);
    }
  } else {
    gemm_f32_kernel<true>
        <<<dim3(3 * ND / 128, M / 128), 256, 0, stream>>>(
            x, Wqkv, qkv, M, 3 * ND, ND);
    flash_attn_mfma<<<dim3(16, 32), 512, 0, stream>>>(qkv, attn);
    gemm_f32_kernel<false>
        <<<dim3(ND / 128, M / 128), 256, 0, stream>>>(
            attn, Wo, out, M, ND, ND);
  }
}

// Round 12
// 714.758 us; speedup vs baseline: 11.4894x; 1.0559x over previous
//
#include <hip/hip_runtime.h>
#include <cstddef>
#include <cstdint>
#include <math.h>

// Problem constants (B=2, S=2048, D=2048, H=16, hd=128)
#define NB 2
#define NS 2048
#define ND 2048
#define NH 16
#define HD 128

typedef __attribute__((ext_vector_type(8))) short short8v;   // 8 bf16 (4 VGPR)
typedef __attribute__((ext_vector_type(4))) float float4v;   // MFMA acc

#define MFMA16(A, B, C) __builtin_amdgcn_mfma_f32_16x16x32_bf16(A, B, C, 0, 0, 0)

// Split fp32 into bf16 hi + bf16 lo (x ~= hi + lo, rel err ~2^-17).
__device__ __forceinline__ void split_bf16(float x, short& hi, short& lo) {
  unsigned u = __float_as_uint(x);
  unsigned hb = (u + 0x7FFFu + ((u >> 16) & 1u)) >> 16;
  float hif = __uint_as_float(hb << 16);
  float r = x - hif;
  unsigned ul = __float_as_uint(r);
  hi = (short)hb;
  lo = (short)((ul + 0x7FFFu + ((ul >> 16) & 1u)) >> 16);
}

__device__ __forceinline__ int pack2(short a, short b) {
  return (int)(unsigned short)a | ((int)(unsigned short)b << 16);
}

// ---------------------------------------------------------------------------
// RoPE cos/sin table: tab[spos][p] = {cos, sin}, spos<2048, p<64. 1 MiB.
// ---------------------------------------------------------------------------
__global__ __launch_bounds__(256) void rope_table_kernel(float2* tab) {
  const int id = blockIdx.x * 256 + threadIdx.x;  // 131072 total
  const int spos = id >> 6, p = id & 63;
  const float invf = powf(10000.f, -(float)p * (1.f / 64.f));
  float s, c;
  sincosf((float)spos * invf, &s, &c);
  tab[id] = make_float2(c, s);
}

// ---------------------------------------------------------------------------
// Elementwise split: in[n4*4] fp32 -> hi, lo bf16 arrays (same layout).
// ---------------------------------------------------------------------------
__global__ __launch_bounds__(256) void split_kernel(
    const float* __restrict__ in, short* __restrict__ hi,
    short* __restrict__ lo, int n4) {
  for (int i = blockIdx.x * 256 + threadIdx.x; i < n4;
       i += gridDim.x * 256) {
    float4 v = ((const float4*)in)[i];
    short h0, l0, h1, l1, h2, l2, h3, l3;
    split_bf16(v.x, h0, l0);
    split_bf16(v.y, h1, l1);
    split_bf16(v.z, h2, l2);
    split_bf16(v.w, h3, l3);
    ((int2*)hi)[i] = make_int2(pack2(h0, h1), pack2(h2, h3));
    ((int2*)lo)[i] = make_int2(pack2(l0, l1), pack2(l2, l3));
  }
}

// ---------------------------------------------------------------------------
// Transpose + split: W[K][N] fp32 -> Th[N][K], Tl[N][K] bf16.
// ---------------------------------------------------------------------------
__global__ __launch_bounds__(256) void transpose_split_kernel(
    const float* __restrict__ W, short* __restrict__ Th, short* __restrict__ Tl,
    int K, int N) {
  __shared__ float T[32][33];
  const int tid = threadIdx.x;
  const int n0 = blockIdx.x * 32, k0 = blockIdx.y * 32;
  {
    const int r = tid >> 3, c4 = (tid & 7) << 2;
    float4 v = *(const float4*)&W[(size_t)(k0 + r) * N + n0 + c4];
    T[r][c4 + 0] = v.x;
    T[r][c4 + 1] = v.y;
    T[r][c4 + 2] = v.z;
    T[r][c4 + 3] = v.w;
  }
  __syncthreads();
  const int n = tid >> 3, k4 = (tid & 7) << 2;
  short h[4], l[4];
#pragma unroll
  for (int e = 0; e < 4; ++e) split_bf16(T[k4 + e][n], h[e], l[e]);
  const size_t off = (size_t)(n0 + n) * K + k0 + k4;
  *(int2*)&Th[off] = make_int2(pack2(h[0], h[1]), pack2(h[2], h[3]));
  *(int2*)&Tl[off] = make_int2(pack2(l[0], l[1]), pack2(l[2], l[3]));
}

// ---------------------------------------------------------------------------
// Split-bf16 MFMA GEMM: C[M,N] = A[M,K] @ W (pre-split BT[N][K] bf16 hi/lo).
// 128x128 tile, BK=32, 256 thr = 4 waves (2x2), 4x4 16x16 frags/wave.
// C = Ah*Bh + Ah*Bl + Al*Bh. ASPLIT: A pre-split to bf16 hi/lo in global
// (pure int4 staging); else A fp32, split inline (round-8 validated path).
// CHX>0: bijective XCD 2D-chunk swizzle (8 XCDs as 4x2, chunks CHX x CHY).
// LDS rows padded to 40 shorts -> <=2-way bank alias. Optional RoPE epilogue.
// ---------------------------------------------------------------------------
template <bool ROPE, bool ASPLIT, int CHX, int CHY>
__global__ __launch_bounds__(256) void gemm_bf16x3_kernel(
    const float* __restrict__ Af, const short* __restrict__ Ahg,
    const short* __restrict__ Alg, const short* __restrict__ BTh,
    const short* __restrict__ BTl, float* __restrict__ C, int M, int N, int K,
    const float2* __restrict__ rope_tab) {
  __shared__ short Ah[128][40], Al[128][40];
  __shared__ short Bh[128][40], Bl[128][40];
  const int tid = threadIdx.x;
  const int wave = tid >> 6, lane = tid & 63;
  const int g = lane >> 4, r = lane & 15;
  const int wy = wave >> 1, wx = wave & 1;

  int bx = blockIdx.x, by = blockIdx.y;
  if (CHX > 0) {  // XCD-aware 2D chunk swizzle (bijective)
    const int flat = by * gridDim.x + bx;
    const int xcd = flat & 7, idx = flat >> 3;
    bx = (xcd & 3) * CHX + idx % CHX;
    by = (xcd >> 2) * CHY + idx / CHX;
  }
  const int m0 = by * 128, n0 = bx * 128;
  const int wm = wy * 64, wn = wx * 64;

  // staging maps: 2 threads per row, 16 elements each
  const int ar = tid >> 1, ac = (tid & 1) << 4;

  const short* bhp = BTh + (size_t)(n0 + ar) * K + ac;
  const short* blp = BTl + (size_t)(n0 + ar) * K + ac;

  float4v acc[4][4];
#pragma unroll
  for (int i = 0; i < 4; ++i)
#pragma unroll
    for (int j = 0; j < 4; ++j) acc[i][j] = (float4v){0.f, 0.f, 0.f, 0.f};

  // prologue: chunk 0 loads
  float4 a0, a1, a2, a3;
  int4 ah0, ah1, al0, al1;
  const float* aptr = nullptr;
  const short* ahp = nullptr;
  const short* alp = nullptr;
  if (ASPLIT) {
    ahp = Ahg + (size_t)(m0 + ar) * K + ac;
    alp = Alg + (size_t)(m0 + ar) * K + ac;
    ah0 = *(const int4*)(ahp);
    ah1 = *(const int4*)(ahp + 8);
    al0 = *(const int4*)(alp);
    al1 = *(const int4*)(alp + 8);
  } else {
    aptr = Af + (size_t)(m0 + ar) * K + ac;
    a0 = *(const float4*)(aptr);
    a1 = *(const float4*)(aptr + 4);
    a2 = *(const float4*)(aptr + 8);
    a3 = *(const float4*)(aptr + 12);
  }
  int4 bh0 = *(const int4*)(bhp);
  int4 bh1 = *(const int4*)(bhp + 8);
  int4 bl0 = *(const int4*)(blp);
  int4 bl1 = *(const int4*)(blp + 8);

  for (int k0 = 0; k0 < K; k0 += 32) {
    __syncthreads();  // previous chunk consumed
    if (ASPLIT) {
      *(int4*)&Ah[ar][ac] = ah0;
      *(int4*)&Ah[ar][ac + 8] = ah1;
      *(int4*)&Al[ar][ac] = al0;
      *(int4*)&Al[ar][ac + 8] = al1;
    } else {
      float xs[16] = {a0.x, a0.y, a0.z, a0.w, a1.x, a1.y, a1.z, a1.w,
                      a2.x, a2.y, a2.z, a2.w, a3.x, a3.y, a3.z, a3.w};
      short h[16], l[16];
#pragma unroll
      for (int e = 0; e < 16; ++e) split_bf16(xs[e], h[e], l[e]);
      *(int4*)&Ah[ar][ac] =
          make_int4(pack2(h[0], h[1]), pack2(h[2], h[3]), pack2(h[4], h[5]),
                    pack2(h[6], h[7]));
      *(int4*)&Ah[ar][ac + 8] =
          make_int4(pack2(h[8], h[9]), pack2(h[10], h[11]),
                    pack2(h[12], h[13]), pack2(h[14], h[15]));
      *(int4*)&Al[ar][ac] =
          make_int4(pack2(l[0], l[1]), pack2(l[2], l[3]), pack2(l[4], l[5]),
                    pack2(l[6], l[7]));
      *(int4*)&Al[ar][ac + 8] =
          make_int4(pack2(l[8], l[9]), pack2(l[10], l[11]),
                    pack2(l[12], l[13]), pack2(l[14], l[15]));
    }
    *(int4*)&Bh[ar][ac] = bh0;
    *(int4*)&Bh[ar][ac + 8] = bh1;
    *(int4*)&Bl[ar][ac] = bl0;
    *(int4*)&Bl[ar][ac + 8] = bl1;
    __syncthreads();
    if (k0 + 32 < K) {  // prefetch next chunk
      if (ASPLIT) {
        ah0 = *(const int4*)(ahp + k0 + 32);
        ah1 = *(const int4*)(ahp + k0 + 40);
        al0 = *(const int4*)(alp + k0 + 32);
        al1 = *(const int4*)(alp + k0 + 40);
      } else {
        const float* an = aptr + k0 + 32;
        a0 = *(const float4*)(an);
        a1 = *(const float4*)(an + 4);
        a2 = *(const float4*)(an + 8);
        a3 = *(const float4*)(an + 12);
      }
      bh0 = *(const int4*)(bhp + k0 + 32);
      bh1 = *(const int4*)(bhp + k0 + 40);
      bl0 = *(const int4*)(blp + k0 + 32);
      bl1 = *(const int4*)(blp + k0 + 40);
    }
    // fragments + MFMA
    short8v afh[4], afl[4], bfh[4], bfl[4];
#pragma unroll
    for (int mi = 0; mi < 4; ++mi) {
      afh[mi] = *(const short8v*)&Ah[wm + mi * 16 + r][8 * g];
      afl[mi] = *(const short8v*)&Al[wm + mi * 16 + r][8 * g];
    }
#pragma unroll
    for (int nj = 0; nj < 4; ++nj) {
      bfh[nj] = *(const short8v*)&Bh[wn + nj * 16 + r][8 * g];
      bfl[nj] = *(const short8v*)&Bl[wn + nj * 16 + r][8 * g];
    }
#pragma unroll
    for (int mi = 0; mi < 4; ++mi)
#pragma unroll
      for (int nj = 0; nj < 4; ++nj) {
        acc[mi][nj] = MFMA16(afh[mi], bfh[nj], acc[mi][nj]);
        acc[mi][nj] = MFMA16(afh[mi], bfl[nj], acc[mi][nj]);
        acc[mi][nj] = MFMA16(afl[mi], bfh[nj], acc[mi][nj]);
      }
  }

  if (ROPE && n0 < 2 * ND) {  // q,k slabs only (v passthrough)
    int p[4];
#pragma unroll
    for (int nj = 0; nj < 4; ++nj)
      p[nj] = ((n0 + wn + nj * 16 + r) & (HD - 1)) >> 1;
    const bool even = (r & 1) == 0;
#pragma unroll
    for (int mi = 0; mi < 4; ++mi)
#pragma unroll
      for (int j = 0; j < 4; ++j) {
        const int spos = (m0 + wm + mi * 16 + 4 * g + j) & (NS - 1);
#pragma unroll
        for (int nj = 0; nj < 4; ++nj) {
          const float2 cs = rope_tab[spos * 64 + p[nj]];
          const float own = acc[mi][nj][j];
          const float oth = __shfl_xor(own, 1);
          acc[mi][nj][j] = even ? own * cs.x - oth * cs.y
                                : oth * cs.y + own * cs.x;
        }
      }
  }
#pragma unroll
  for (int mi = 0; mi < 4; ++mi)
#pragma unroll
    for (int j = 0; j < 4; ++j) {
      const size_t row = m0 + wm + mi * 16 + 4 * g + j;
      float* Crow = C + row * N + n0 + wn;
#pragma unroll
      for (int nj = 0; nj < 4; ++nj) Crow[nj * 16 + r] = acc[mi][nj][j];
    }
}

// ---------------------------------------------------------------------------
// Fallback tiled fp32 GEMM (validated round-5/6 kernel, unchanged).
// ---------------------------------------------------------------------------
template <bool ROPE>
__global__ __launch_bounds__(256) void gemm_f32_kernel(
    const float* __restrict__ A, const float* __restrict__ Bm,
    float* __restrict__ C, int M, int N, int K) {
  __shared__ float As[16][132];
  __shared__ float Bs[16][132];
  const int tid = threadIdx.x;
  const int m0 = blockIdx.y * 128;
  const int n0 = blockIdx.x * 128;
  const int tr = tid >> 4;
  const int tc = tid & 15;
  const int la_r = tid >> 1;
  const int la_c = (tid & 1) << 3;
  const int lb_r = tid >> 4;
  const int lb_c = (tid & 15) << 3;

  const float* Aptr = A + (size_t)(m0 + la_r) * K + la_c;
  const float* Bptr = Bm + (size_t)lb_r * N + n0 + lb_c;

  float acc[8][8] = {};

  float4 av0 = *(const float4*)(Aptr);
  float4 av1 = *(const float4*)(Aptr + 4);
  float4 bv0 = *(const float4*)(Bptr);
  float4 bv1 = *(const float4*)(Bptr + 4);

  for (int k0 = 0; k0 < K; k0 += 16) {
    __syncthreads();
    As[la_c + 0][la_r] = av0.x;
    As[la_c + 1][la_r] = av0.y;
    As[la_c + 2][la_r] = av0.z;
    As[la_c + 3][la_r] = av0.w;
    As[la_c + 4][la_r] = av1.x;
    As[la_c + 5][la_r] = av1.y;
    As[la_c + 6][la_r] = av1.z;
    As[la_c + 7][la_r] = av1.w;
    *(float4*)&Bs[lb_r][lb_c] = bv0;
    *(float4*)&Bs[lb_r][lb_c + 4] = bv1;
    __syncthreads();
    if (k0 + 16 < K) {
      const float* An = Aptr + k0 + 16;
      const float* Bn = Bptr + (size_t)(k0 + 16) * N;
      av0 = *(const float4*)(An);
      av1 = *(const float4*)(An + 4);
      bv0 = *(const float4*)(Bn);
      bv1 = *(const float4*)(Bn + 4);
    }
#pragma unroll
    for (int kk = 0; kk < 16; ++kk) {
      float a[8], b[8];
      *(float4*)&a[0] = *(const float4*)&As[kk][tr << 2];
      *(float4*)&a[4] = *(const float4*)&As[kk][64 + (tr << 2)];
      *(float4*)&b[0] = *(const float4*)&Bs[kk][tc << 2];
      *(float4*)&b[4] = *(const float4*)&Bs[kk][64 + (tc << 2)];
#pragma unroll
      for (int i = 0; i < 8; ++i)
#pragma unroll
        for (int j = 0; j < 8; ++j) acc[i][j] = fmaf(a[i], b[j], acc[i][j]);
    }
  }

  if (ROPE) {
    if ((n0 >> 11) < 2) {
#pragma unroll
      for (int g = 0; g < 2; ++g) {
        const int col = n0 + g * 64 + (tc << 2);
        const int d0 = col & (HD - 1);
        const int p0 = d0 >> 1;
        const float invf0 = powf(10000.f, -(float)p0 * (1.f / 64.f));
        const float invf1 = powf(10000.f, -(float)(p0 + 1) * (1.f / 64.f));
#pragma unroll
        for (int rg = 0; rg < 2; ++rg) {
#pragma unroll
          for (int i = 0; i < 4; ++i) {
            const int row = m0 + rg * 64 + (tr << 2) + i;
            const int spos = row & (NS - 1);
            float s0, c0, s1, c1;
            sincosf((float)spos * invf0, &s0, &c0);
            sincosf((float)spos * invf1, &s1, &c1);
            float* ar2 = &acc[rg * 4 + i][g * 4];
            const float xe0 = ar2[0], xo0 = ar2[1];
            const float xe1 = ar2[2], xo1 = ar2[3];
            ar2[0] = xe0 * c0 - xo0 * s0;
            ar2[1] = xe0 * s0 + xo0 * c0;
            ar2[2] = xe1 * c1 - xo1 * s1;
            ar2[3] = xe1 * s1 + xo1 * c1;
          }
        }
      }
    }
  }
#pragma unroll
  for (int rg = 0; rg < 2; ++rg) {
#pragma unroll
    for (int i = 0; i < 4; ++i) {
      const size_t row = m0 + rg * 64 + (tr << 2) + i;
      float* Crow = C + row * N + n0;
      float4 v0 = make_float4(acc[rg * 4 + i][0], acc[rg * 4 + i][1],
                              acc[rg * 4 + i][2], acc[rg * 4 + i][3]);
      float4 v1 = make_float4(acc[rg * 4 + i][4], acc[rg * 4 + i][5],
                              acc[rg * 4 + i][6], acc[rg * 4 + i][7]);
      *(float4*)(Crow + (tc << 2)) = v0;
      *(float4*)(Crow + 64 + (tc << 2)) = v1;
    }
  }
}

// ---------------------------------------------------------------------------
// Flash attention via split-bf16 MFMA (validated round-6 kernel, unchanged).
// ---------------------------------------------------------------------------
__global__ __launch_bounds__(512) void flash_attn_mfma(
    const float* __restrict__ qkv, float* __restrict__ O) {
  __shared__ short Khi[32][136];
  __shared__ short Klo[32][136];
  __shared__ short Vthi[128][40];
  __shared__ short Vtlo[128][40];
  __shared__ short Phi[8][16][40];
  __shared__ short Plo[8][16][40];

  const int tid = threadIdx.x;
  const int lane = tid & 63;
  const int wave = tid >> 6;
  const int g = lane >> 4;
  const int r = lane & 15;
  const int qtile = 15 - blockIdx.x;
  const int bh = blockIdx.y;
  const int b = bh >> 4, h = bh & 15;
  const int qb = qtile << 7;
  const int qw = qb + (wave << 4);
  const size_t row3d = 3 * ND;
  const float* base = qkv + (size_t)b * NS * row3d + (size_t)h * HD;
  const float* Kg = base + ND;
  const float* Vg = base + 2 * ND;

  const float scale = 0.088388347648318447f;
  const float* Qrow = base + (size_t)(qw + r) * row3d;
  short8v qhi[4], qlo[4];
#pragma unroll
  for (int hf = 0; hf < 4; ++hf) {
    const float* p = Qrow + 32 * hf + 8 * g;
    float4 x0 = *(const float4*)(p);
    float4 x1 = *(const float4*)(p + 4);
    float xs[8] = {x0.x, x0.y, x0.z, x0.w, x1.x, x1.y, x1.z, x1.w};
#pragma unroll
    for (int i = 0; i < 8; ++i) {
      short hi_, lo_;
      split_bf16(xs[i] * scale, hi_, lo_);
      qhi[hf][i] = hi_;
      qlo[hf][i] = lo_;
    }
  }

  float4v acc[8];
#pragma unroll
  for (int i = 0; i < 8; ++i) acc[i] = (float4v){0.f, 0.f, 0.f, 0.f};
  float m_run = -INFINITY;
  float l_run = 0.f;

  const int skv = tid >> 4;
  const int shd = (tid & 15) << 3;
  const int vkv = (tid & 15) << 1;
  const int vhd = (tid >> 4) << 2;
  const int ntiles = (qtile + 1) << 2;

  for (int t = 0; t < ntiles; ++t) {
    const int kvb = t << 5;
    __syncthreads();
    {
      const float* kr = Kg + (size_t)(kvb + skv) * row3d + shd;
#pragma unroll
      for (int u = 0; u < 2; ++u) {
        float4 v = *(const float4*)(kr + 4 * u);
        short h0, l0, h1, l1, h2, l2, h3, l3;
        split_bf16(v.x, h0, l0);
        split_bf16(v.y, h1, l1);
        split_bf16(v.z, h2, l2);
        split_bf16(v.w, h3, l3);
        *(int2*)&Khi[skv][shd + 4 * u] =
            make_int2(pack2(h0, h1), pack2(h2, h3));
        *(int2*)&Klo[skv][shd + 4 * u] =
            make_int2(pack2(l0, l1), pack2(l2, l3));
      }
    }
    {
      const float* v0p = Vg + (size_t)(kvb + vkv) * row3d + vhd;
      const float* v1p = v0p + row3d;
      float4 a0 = *(const float4*)(v0p);
      float4 b0 = *(const float4*)(v1p);
      float e0[4] = {a0.x, a0.y, a0.z, a0.w};
      float e1[4] = {b0.x, b0.y, b0.z, b0.w};
#pragma unroll
      for (int e = 0; e < 4; ++e) {
        short h0, l0, h1, l1;
        split_bf16(e0[e], h0, l0);
        split_bf16(e1[e], h1, l1);
        *(int*)&Vthi[vhd + e][vkv] = pack2(h0, h1);
        *(int*)&Vtlo[vhd + e][vkv] = pack2(l0, l1);
      }
    }
    __syncthreads();

    if (kvb <= qw + 15) {
      float4v s4[2];
#pragma unroll
      for (int f = 0; f < 2; ++f) s4[f] = (float4v){0.f, 0.f, 0.f, 0.f};
#pragma unroll
      for (int f = 0; f < 2; ++f) {
#pragma unroll
        for (int hf = 0; hf < 4; ++hf) {
          short8v ka = *(const short8v*)&Khi[16 * f + r][32 * hf + 8 * g];
          short8v kb = *(const short8v*)&Klo[16 * f + r][32 * hf + 8 * g];
          s4[f] = MFMA16(ka, qhi[hf], s4[f]);
          s4[f] = MFMA16(ka, qlo[hf], s4[f]);
          s4[f] = MFMA16(kb, qhi[hf], s4[f]);
        }
      }
      const int qglob = qw + r;
      if (kvb + 31 > qw) {
#pragma unroll
        for (int f = 0; f < 2; ++f)
#pragma unroll
          for (int j = 0; j < 4; ++j)
            if (kvb + 16 * f + 4 * g + j > qglob) s4[f][j] = -INFINITY;
      }
      float tmax = s4[0][0];
#pragma unroll
      for (int f = 0; f < 2; ++f)
#pragma unroll
        for (int j = 0; j < 4; ++j) tmax = fmaxf(tmax, s4[f][j]);
      tmax = fmaxf(tmax, __shfl_xor(tmax, 16));
      tmax = fmaxf(tmax, __shfl_xor(tmax, 32));
      const float mnew = fmaxf(m_run, tmax);
      const float alpha = __expf(m_run - mnew);
      float psum = 0.f;
      short ph[8], pl[8];
#pragma unroll
      for (int f = 0; f < 2; ++f)
#pragma unroll
        for (int j = 0; j < 4; ++j) {
          float p = __expf(s4[f][j] - mnew);
          psum += p;
          split_bf16(p, ph[4 * f + j], pl[4 * f + j]);
        }
      psum += __shfl_xor(psum, 16);
      psum += __shfl_xor(psum, 32);
      l_run = l_run * alpha + psum;
      m_run = mnew;
#pragma unroll
      for (int f = 0; f < 2; ++f) {
        *(int2*)&Phi[wave][r][16 * f + 4 * g] = make_int2(
            pack2(ph[4 * f + 0], ph[4 * f + 1]),
            pack2(ph[4 * f + 2], ph[4 * f + 3]));
        *(int2*)&Plo[wave][r][16 * f + 4 * g] = make_int2(
            pack2(pl[4 * f + 0], pl[4 * f + 1]),
            pack2(pl[4 * f + 2], pl[4 * f + 3]));
      }
      float aj[4];
#pragma unroll
      for (int j = 0; j < 4; ++j) aj[j] = __shfl(alpha, 4 * g + j);
#pragma unroll
      for (int hf = 0; hf < 8; ++hf)
#pragma unroll
        for (int j = 0; j < 4; ++j) acc[hf][j] *= aj[j];
      short8v pa = *(const short8v*)&Phi[wave][r][8 * g];
      short8v pb = *(const short8v*)&Plo[wave][r][8 * g];
#pragma unroll
      for (int hf = 0; hf < 8; ++hf) {
        short8v va = *(const short8v*)&Vthi[16 * hf + r][8 * g];
        short8v vb = *(const short8v*)&Vtlo[16 * hf + r][8 * g];
        acc[hf] = MFMA16(pa, va, acc[hf]);
        acc[hf] = MFMA16(pa, vb, acc[hf]);
        acc[hf] = MFMA16(pb, va, acc[hf]);
      }
    }
  }
  const float il = 1.f / l_run;
  float lj[4];
#pragma unroll
  for (int j = 0; j < 4; ++j) lj[j] = __shfl(il, 4 * g + j);
  float* Ob = O + ((size_t)b * NS + qw) * ND + h * HD;
#pragma unroll
  for (int hf = 0; hf < 8; ++hf)
#pragma unroll
    for (int j = 0; j < 4; ++j)
      Ob[(size_t)(4 * g + j) * ND + 16 * hf + r] = acc[hf][j] * lj[j];
}

// ---------------------------------------------------------------------------
// Launch. Full layout now 225 MiB (fits 256 MiB ws): qkv f32 | attn f32 |
// WqkvT hi/lo | WoT hi/lo | rope tab | xh/xl. KEY: ath/atl ALIAS xh/xl —
// x splits are dead after the QKV GEMM, and stream order serializes
// attention -> attn-split -> out-GEMM, so reuse is race-free.
// Fallback tiers: base (202 MiB, inline-split A) -> fp32 GEMMs.
// ---------------------------------------------------------------------------
extern "C" void kernel_launch(void* const* d_in, const int* in_sizes, int n_in,
                              void* d_out, int out_size, void* d_ws,
                              size_t ws_size, hipStream_t stream) {
  const float* x = (const float*)d_in[0];
  const float* Wqkv = (const float*)d_in[1];
  const float* Wo = (const float*)d_in[2];
  float* out = (float*)d_out;
  float* qkv = (float*)d_ws;                       // 25165824 f
  float* attn = qkv + (size_t)NB * NS * 3 * ND;    // 8388608 f
  short* wqh = (short*)(attn + (size_t)NB * NS * ND);  // 12582912 s each
  short* wql = wqh + (size_t)ND * 3 * ND;
  short* woh = wql + (size_t)ND * 3 * ND;          // 4194304 s each
  short* wol = woh + (size_t)ND * ND;
  float2* tab = (float2*)(wol + (size_t)ND * ND);  // 131072 float2
  short* xh = (short*)(tab + (size_t)NS * 64);     // 8388608 s each
  short* xl = xh + (size_t)NB * NS * ND;
  short* ath = xh;  // ALIAS: x splits dead after QKV GEMM
  short* atl = xl;

  const size_t base_need =
      ((size_t)NB * NS * 3 * ND + (size_t)NB * NS * ND) * 4 +
      ((size_t)ND * 3 * ND + (size_t)ND * ND) * 2 * 2 + (size_t)NS * 64 * 8;
  const size_t full_need = base_need + (size_t)NB * NS * ND * 2 * 2;

  const int M = NB * NS;
  if (ws_size >= base_need) {
    rope_table_kernel<<<NS * 64 / 256, 256, 0, stream>>>(tab);
    transpose_split_kernel<<<dim3(3 * ND / 32, ND / 32), 256, 0, stream>>>(
        Wqkv, wqh, wql, ND, 3 * ND);
    transpose_split_kernel<<<dim3(ND / 32, ND / 32), 256, 0, stream>>>(
        Wo, woh, wol, ND, ND);
    if (ws_size >= full_need) {
      split_kernel<<<2048, 256, 0, stream>>>(x, xh, xl, M * ND / 4);
      gemm_bf16x3_kernel<true, true, 12, 16>
          <<<dim3(3 * ND / 128, M / 128), 256, 0, stream>>>(
              nullptr, xh, xl, wqh, wql, qkv, M, 3 * ND, ND, tab);
      flash_attn_mfma<<<dim3(16, 32), 512, 0, stream>>>(qkv, attn);
      split_kernel<<<2048, 256, 0, stream>>>(attn, ath, atl, M * ND / 4);
      gemm_bf16x3_kernel<false, true, 4, 16>
          <<<dim3(ND / 128, M / 128), 256, 0, stream>>>(
              nullptr, ath, atl, woh, wol, out, M, ND, ND, tab);
    } else {
      gemm_bf16x3_kernel<true, false, 0, 0>
          <<<dim3(3 * ND / 128, M / 128), 256, 0, stream>>>(
              x, nullptr, nullptr, wqh, wql, qkv, M, 3 * ND, ND, tab);
      flash_attn_mfma<<<dim3(16, 32), 512, 0, stream>>>(qkv, attn);
      gemm_bf16x3_kernel<false, false, 0, 0>
          <<<dim3(ND / 128, M / 128), 256, 0, stream>>>(
              attn, nullptr, nullptr, woh, wol, out, M, ND, ND, tab);
    }
  } else {
    gemm_f32_kernel<true>
        <<<dim3(3 * ND / 128, M / 128), 256, 0, stream>>>(
            x, Wqkv, qkv, M, 3 * ND, ND);
    flash_attn_mfma<<<dim3(16, 32), 512, 0, stream>>>(qkv, attn);
    gemm_f32_kernel<false>
        <<<dim3(ND / 128, M / 128), 256, 0, stream>>>(
            attn, Wo, out, M, ND, ND);
  }
}

// Round 13
// 710.028 us; speedup vs baseline: 11.5659x; 1.0067x over previous
//
#include <hip/hip_runtime.h>
#include <cstddef>
#include <cstdint>
#include <math.h>

// Problem constants (B=2, S=2048, D=2048, H=16, hd=128)
#define NB 2
#define NS 2048
#define ND 2048
#define NH 16
#define HD 128

typedef __attribute__((ext_vector_type(8))) short short8v;   // 8 bf16 (4 VGPR)
typedef __attribute__((ext_vector_type(4))) float float4v;   // MFMA acc

#define MFMA16(A, B, C) __builtin_amdgcn_mfma_f32_16x16x32_bf16(A, B, C, 0, 0, 0)

// Split fp32 into bf16 hi + bf16 lo (x ~= hi + lo, rel err ~2^-17).
__device__ __forceinline__ void split_bf16(float x, short& hi, short& lo) {
  unsigned u = __float_as_uint(x);
  unsigned hb = (u + 0x7FFFu + ((u >> 16) & 1u)) >> 16;
  float hif = __uint_as_float(hb << 16);
  float r = x - hif;
  unsigned ul = __float_as_uint(r);
  hi = (short)hb;
  lo = (short)((ul + 0x7FFFu + ((ul >> 16) & 1u)) >> 16);
}

__device__ __forceinline__ int pack2(short a, short b) {
  return (int)(unsigned short)a | ((int)(unsigned short)b << 16);
}

// ---------------------------------------------------------------------------
// RoPE cos/sin table: tab[spos][p] = {cos, sin}, spos<2048, p<64. 1 MiB.
// ---------------------------------------------------------------------------
__global__ __launch_bounds__(256) void rope_table_kernel(float2* tab) {
  const int id = blockIdx.x * 256 + threadIdx.x;  // 131072 total
  const int spos = id >> 6, p = id & 63;
  const float invf = powf(10000.f, -(float)p * (1.f / 64.f));
  float s, c;
  sincosf((float)spos * invf, &s, &c);
  tab[id] = make_float2(c, s);
}

// ---------------------------------------------------------------------------
// Elementwise split: in[n4*4] fp32 -> hi, lo bf16 arrays (same layout).
// ---------------------------------------------------------------------------
__global__ __launch_bounds__(256) void split_kernel(
    const float* __restrict__ in, short* __restrict__ hi,
    short* __restrict__ lo, int n4) {
  for (int i = blockIdx.x * 256 + threadIdx.x; i < n4;
       i += gridDim.x * 256) {
    float4 v = ((const float4*)in)[i];
    short h0, l0, h1, l1, h2, l2, h3, l3;
    split_bf16(v.x, h0, l0);
    split_bf16(v.y, h1, l1);
    split_bf16(v.z, h2, l2);
    split_bf16(v.w, h3, l3);
    ((int2*)hi)[i] = make_int2(pack2(h0, h1), pack2(h2, h3));
    ((int2*)lo)[i] = make_int2(pack2(l0, l1), pack2(l2, l3));
  }
}

// ---------------------------------------------------------------------------
// Transpose + split: W[K][N] fp32 -> Th[N][K], Tl[N][K] bf16.
// ---------------------------------------------------------------------------
__global__ __launch_bounds__(256) void transpose_split_kernel(
    const float* __restrict__ W, short* __restrict__ Th, short* __restrict__ Tl,
    int K, int N) {
  __shared__ float T[32][33];
  const int tid = threadIdx.x;
  const int n0 = blockIdx.x * 32, k0 = blockIdx.y * 32;
  {
    const int r = tid >> 3, c4 = (tid & 7) << 2;
    float4 v = *(const float4*)&W[(size_t)(k0 + r) * N + n0 + c4];
    T[r][c4 + 0] = v.x;
    T[r][c4 + 1] = v.y;
    T[r][c4 + 2] = v.z;
    T[r][c4 + 3] = v.w;
  }
  __syncthreads();
  const int n = tid >> 3, k4 = (tid & 7) << 2;
  short h[4], l[4];
#pragma unroll
  for (int e = 0; e < 4; ++e) split_bf16(T[k4 + e][n], h[e], l[e]);
  const size_t off = (size_t)(n0 + n) * K + k0 + k4;
  *(int2*)&Th[off] = make_int2(pack2(h[0], h[1]), pack2(h[2], h[3]));
  *(int2*)&Tl[off] = make_int2(pack2(l[0], l[1]), pack2(l[2], l[3]));
}

// ---------------------------------------------------------------------------
// Split-bf16 MFMA GEMM: C[M,N] = A[M,K] @ W (pre-split BT[N][K] bf16 hi/lo).
// 128x128 tile, BK=32, 256 thr = 4 waves (2x2), 4x4 16x16 frags/wave.
// C = Ah*Bh + Ah*Bl + Al*Bh. ASPLIT: A pre-split to bf16 hi/lo in global
// (pure int4 staging); else A fp32, split inline (round-8 validated path).
// CHX>0: bijective XCD 2D-chunk swizzle (8 XCDs as 4x2, chunks CHX x CHY).
// LDS rows padded to 40 shorts -> <=2-way bank alias. Optional RoPE epilogue.
// ---------------------------------------------------------------------------
template <bool ROPE, bool ASPLIT, int CHX, int CHY>
__global__ __launch_bounds__(256) void gemm_bf16x3_kernel(
    const float* __restrict__ Af, const short* __restrict__ Ahg,
    const short* __restrict__ Alg, const short* __restrict__ BTh,
    const short* __restrict__ BTl, float* __restrict__ C, int M, int N, int K,
    const float2* __restrict__ rope_tab) {
  __shared__ short Ah[128][40], Al[128][40];
  __shared__ short Bh[128][40], Bl[128][40];
  const int tid = threadIdx.x;
  const int wave = tid >> 6, lane = tid & 63;
  const int g = lane >> 4, r = lane & 15;
  const int wy = wave >> 1, wx = wave & 1;

  int bx = blockIdx.x, by = blockIdx.y;
  if (CHX > 0) {  // XCD-aware 2D chunk swizzle (bijective)
    const int flat = by * gridDim.x + bx;
    const int xcd = flat & 7, idx = flat >> 3;
    bx = (xcd & 3) * CHX + idx % CHX;
    by = (xcd >> 2) * CHY + idx / CHX;
  }
  const int m0 = by * 128, n0 = bx * 128;
  const int wm = wy * 64, wn = wx * 64;

  // staging maps: 2 threads per row, 16 elements each
  const int ar = tid >> 1, ac = (tid & 1) << 4;

  const short* bhp = BTh + (size_t)(n0 + ar) * K + ac;
  const short* blp = BTl + (size_t)(n0 + ar) * K + ac;

  float4v acc[4][4];
#pragma unroll
  for (int i = 0; i < 4; ++i)
#pragma unroll
    for (int j = 0; j < 4; ++j) acc[i][j] = (float4v){0.f, 0.f, 0.f, 0.f};

  // prologue: chunk 0 loads
  float4 a0, a1, a2, a3;
  int4 ah0, ah1, al0, al1;
  const float* aptr = nullptr;
  const short* ahp = nullptr;
  const short* alp = nullptr;
  if (ASPLIT) {
    ahp = Ahg + (size_t)(m0 + ar) * K + ac;
    alp = Alg + (size_t)(m0 + ar) * K + ac;
    ah0 = *(const int4*)(ahp);
    ah1 = *(const int4*)(ahp + 8);
    al0 = *(const int4*)(alp);
    al1 = *(const int4*)(alp + 8);
  } else {
    aptr = Af + (size_t)(m0 + ar) * K + ac;
    a0 = *(const float4*)(aptr);
    a1 = *(const float4*)(aptr + 4);
    a2 = *(const float4*)(aptr + 8);
    a3 = *(const float4*)(aptr + 12);
  }
  int4 bh0 = *(const int4*)(bhp);
  int4 bh1 = *(const int4*)(bhp + 8);
  int4 bl0 = *(const int4*)(blp);
  int4 bl1 = *(const int4*)(blp + 8);

  for (int k0 = 0; k0 < K; k0 += 32) {
    __syncthreads();  // previous chunk consumed
    if (ASPLIT) {
      *(int4*)&Ah[ar][ac] = ah0;
      *(int4*)&Ah[ar][ac + 8] = ah1;
      *(int4*)&Al[ar][ac] = al0;
      *(int4*)&Al[ar][ac + 8] = al1;
    } else {
      float xs[16] = {a0.x, a0.y, a0.z, a0.w, a1.x, a1.y, a1.z, a1.w,
                      a2.x, a2.y, a2.z, a2.w, a3.x, a3.y, a3.z, a3.w};
      short h[16], l[16];
#pragma unroll
      for (int e = 0; e < 16; ++e) split_bf16(xs[e], h[e], l[e]);
      *(int4*)&Ah[ar][ac] =
          make_int4(pack2(h[0], h[1]), pack2(h[2], h[3]), pack2(h[4], h[5]),
                    pack2(h[6], h[7]));
      *(int4*)&Ah[ar][ac + 8] =
          make_int4(pack2(h[8], h[9]), pack2(h[10], h[11]),
                    pack2(h[12], h[13]), pack2(h[14], h[15]));
      *(int4*)&Al[ar][ac] =
          make_int4(pack2(l[0], l[1]), pack2(l[2], l[3]), pack2(l[4], l[5]),
                    pack2(l[6], l[7]));
      *(int4*)&Al[ar][ac + 8] =
          make_int4(pack2(l[8], l[9]), pack2(l[10], l[11]),
                    pack2(l[12], l[13]), pack2(l[14], l[15]));
    }
    *(int4*)&Bh[ar][ac] = bh0;
    *(int4*)&Bh[ar][ac + 8] = bh1;
    *(int4*)&Bl[ar][ac] = bl0;
    *(int4*)&Bl[ar][ac + 8] = bl1;
    __syncthreads();
    if (k0 + 32 < K) {  // prefetch next chunk
      if (ASPLIT) {
        ah0 = *(const int4*)(ahp + k0 + 32);
        ah1 = *(const int4*)(ahp + k0 + 40);
        al0 = *(const int4*)(alp + k0 + 32);
        al1 = *(const int4*)(alp + k0 + 40);
      } else {
        const float* an = aptr + k0 + 32;
        a0 = *(const float4*)(an);
        a1 = *(const float4*)(an + 4);
        a2 = *(const float4*)(an + 8);
        a3 = *(const float4*)(an + 12);
      }
      bh0 = *(const int4*)(bhp + k0 + 32);
      bh1 = *(const int4*)(bhp + k0 + 40);
      bl0 = *(const int4*)(blp + k0 + 32);
      bl1 = *(const int4*)(blp + k0 + 40);
    }
    // fragments + MFMA
    short8v afh[4], afl[4], bfh[4], bfl[4];
#pragma unroll
    for (int mi = 0; mi < 4; ++mi) {
      afh[mi] = *(const short8v*)&Ah[wm + mi * 16 + r][8 * g];
      afl[mi] = *(const short8v*)&Al[wm + mi * 16 + r][8 * g];
    }
#pragma unroll
    for (int nj = 0; nj < 4; ++nj) {
      bfh[nj] = *(const short8v*)&Bh[wn + nj * 16 + r][8 * g];
      bfl[nj] = *(const short8v*)&Bl[wn + nj * 16 + r][8 * g];
    }
#pragma unroll
    for (int mi = 0; mi < 4; ++mi)
#pragma unroll
      for (int nj = 0; nj < 4; ++nj) {
        acc[mi][nj] = MFMA16(afh[mi], bfh[nj], acc[mi][nj]);
        acc[mi][nj] = MFMA16(afh[mi], bfl[nj], acc[mi][nj]);
        acc[mi][nj] = MFMA16(afl[mi], bfh[nj], acc[mi][nj]);
      }
  }

  if (ROPE && n0 < 2 * ND) {  // q,k slabs only (v passthrough)
    int p[4];
#pragma unroll
    for (int nj = 0; nj < 4; ++nj)
      p[nj] = ((n0 + wn + nj * 16 + r) & (HD - 1)) >> 1;
    const bool even = (r & 1) == 0;
#pragma unroll
    for (int mi = 0; mi < 4; ++mi)
#pragma unroll
      for (int j = 0; j < 4; ++j) {
        const int spos = (m0 + wm + mi * 16 + 4 * g + j) & (NS - 1);
#pragma unroll
        for (int nj = 0; nj < 4; ++nj) {
          const float2 cs = rope_tab[spos * 64 + p[nj]];
          const float own = acc[mi][nj][j];
          const float oth = __shfl_xor(own, 1);
          acc[mi][nj][j] = even ? own * cs.x - oth * cs.y
                                : oth * cs.y + own * cs.x;
        }
      }
  }
#pragma unroll
  for (int mi = 0; mi < 4; ++mi)
#pragma unroll
    for (int j = 0; j < 4; ++j) {
      const size_t row = m0 + wm + mi * 16 + 4 * g + j;
      float* Crow = C + row * N + n0 + wn;
#pragma unroll
      for (int nj = 0; nj < 4; ++nj) Crow[nj * 16 + r] = acc[mi][nj][j];
    }
}

// ---------------------------------------------------------------------------
// Fallback tiled fp32 GEMM (validated round-5/6 kernel, unchanged).
// ---------------------------------------------------------------------------
template <bool ROPE>
__global__ __launch_bounds__(256) void gemm_f32_kernel(
    const float* __restrict__ A, const float* __restrict__ Bm,
    float* __restrict__ C, int M, int N, int K) {
  __shared__ float As[16][132];
  __shared__ float Bs[16][132];
  const int tid = threadIdx.x;
  const int m0 = blockIdx.y * 128;
  const int n0 = blockIdx.x * 128;
  const int tr = tid >> 4;
  const int tc = tid & 15;
  const int la_r = tid >> 1;
  const int la_c = (tid & 1) << 3;
  const int lb_r = tid >> 4;
  const int lb_c = (tid & 15) << 3;

  const float* Aptr = A + (size_t)(m0 + la_r) * K + la_c;
  const float* Bptr = Bm + (size_t)lb_r * N + n0 + lb_c;

  float acc[8][8] = {};

  float4 av0 = *(const float4*)(Aptr);
  float4 av1 = *(const float4*)(Aptr + 4);
  float4 bv0 = *(const float4*)(Bptr);
  float4 bv1 = *(const float4*)(Bptr + 4);

  for (int k0 = 0; k0 < K; k0 += 16) {
    __syncthreads();
    As[la_c + 0][la_r] = av0.x;
    As[la_c + 1][la_r] = av0.y;
    As[la_c + 2][la_r] = av0.z;
    As[la_c + 3][la_r] = av0.w;
    As[la_c + 4][la_r] = av1.x;
    As[la_c + 5][la_r] = av1.y;
    As[la_c + 6][la_r] = av1.z;
    As[la_c + 7][la_r] = av1.w;
    *(float4*)&Bs[lb_r][lb_c] = bv0;
    *(float4*)&Bs[lb_r][lb_c + 4] = bv1;
    __syncthreads();
    if (k0 + 16 < K) {
      const float* An = Aptr + k0 + 16;
      const float* Bn = Bptr + (size_t)(k0 + 16) * N;
      av0 = *(const float4*)(An);
      av1 = *(const float4*)(An + 4);
      bv0 = *(const float4*)(Bn);
      bv1 = *(const float4*)(Bn + 4);
    }
#pragma unroll
    for (int kk = 0; kk < 16; ++kk) {
      float a[8], b[8];
      *(float4*)&a[0] = *(const float4*)&As[kk][tr << 2];
      *(float4*)&a[4] = *(const float4*)&As[kk][64 + (tr << 2)];
      *(float4*)&b[0] = *(const float4*)&Bs[kk][tc << 2];
      *(float4*)&b[4] = *(const float4*)&Bs[kk][64 + (tc << 2)];
#pragma unroll
      for (int i = 0; i < 8; ++i)
#pragma unroll
        for (int j = 0; j < 8; ++j) acc[i][j] = fmaf(a[i], b[j], acc[i][j]);
    }
  }

  if (ROPE) {
    if ((n0 >> 11) < 2) {
#pragma unroll
      for (int g = 0; g < 2; ++g) {
        const int col = n0 + g * 64 + (tc << 2);
        const int d0 = col & (HD - 1);
        const int p0 = d0 >> 1;
        const float invf0 = powf(10000.f, -(float)p0 * (1.f / 64.f));
        const float invf1 = powf(10000.f, -(float)(p0 + 1) * (1.f / 64.f));
#pragma unroll
        for (int rg = 0; rg < 2; ++rg) {
#pragma unroll
          for (int i = 0; i < 4; ++i) {
            const int row = m0 + rg * 64 + (tr << 2) + i;
            const int spos = row & (NS - 1);
            float s0, c0, s1, c1;
            sincosf((float)spos * invf0, &s0, &c0);
            sincosf((float)spos * invf1, &s1, &c1);
            float* ar2 = &acc[rg * 4 + i][g * 4];
            const float xe0 = ar2[0], xo0 = ar2[1];
            const float xe1 = ar2[2], xo1 = ar2[3];
            ar2[0] = xe0 * c0 - xo0 * s0;
            ar2[1] = xe0 * s0 + xo0 * c0;
            ar2[2] = xe1 * c1 - xo1 * s1;
            ar2[3] = xe1 * s1 + xo1 * c1;
          }
        }
      }
    }
  }
#pragma unroll
  for (int rg = 0; rg < 2; ++rg) {
#pragma unroll
    for (int i = 0; i < 4; ++i) {
      const size_t row = m0 + rg * 64 + (tr << 2) + i;
      float* Crow = C + row * N + n0;
      float4 v0 = make_float4(acc[rg * 4 + i][0], acc[rg * 4 + i][1],
                              acc[rg * 4 + i][2], acc[rg * 4 + i][3]);
      float4 v1 = make_float4(acc[rg * 4 + i][4], acc[rg * 4 + i][5],
                              acc[rg * 4 + i][6], acc[rg * 4 + i][7]);
      *(float4*)(Crow + (tc << 2)) = v0;
      *(float4*)(Crow + 64 + (tc << 2)) = v1;
    }
  }
}

// ---------------------------------------------------------------------------
// Flash attention via split-bf16 MFMA (round-6 validated core).
// SPLITOUT: write output directly as bf16 hi/lo pair (bit-identical to
// fp32-write + separate split kernel) — feeds the out-GEMM's ASPLIT path.
// ---------------------------------------------------------------------------
template <bool SPLITOUT>
__global__ __launch_bounds__(512) void flash_attn_mfma(
    const float* __restrict__ qkv, float* __restrict__ O,
    short* __restrict__ Oh, short* __restrict__ Ol) {
  __shared__ short Khi[32][136];
  __shared__ short Klo[32][136];
  __shared__ short Vthi[128][40];
  __shared__ short Vtlo[128][40];
  __shared__ short Phi[8][16][40];
  __shared__ short Plo[8][16][40];

  const int tid = threadIdx.x;
  const int lane = tid & 63;
  const int wave = tid >> 6;
  const int g = lane >> 4;
  const int r = lane & 15;
  const int qtile = 15 - blockIdx.x;
  const int bh = blockIdx.y;
  const int b = bh >> 4, h = bh & 15;
  const int qb = qtile << 7;
  const int qw = qb + (wave << 4);
  const size_t row3d = 3 * ND;
  const float* base = qkv + (size_t)b * NS * row3d + (size_t)h * HD;
  const float* Kg = base + ND;
  const float* Vg = base + 2 * ND;

  const float scale = 0.088388347648318447f;
  const float* Qrow = base + (size_t)(qw + r) * row3d;
  short8v qhi[4], qlo[4];
#pragma unroll
  for (int hf = 0; hf < 4; ++hf) {
    const float* p = Qrow + 32 * hf + 8 * g;
    float4 x0 = *(const float4*)(p);
    float4 x1 = *(const float4*)(p + 4);
    float xs[8] = {x0.x, x0.y, x0.z, x0.w, x1.x, x1.y, x1.z, x1.w};
#pragma unroll
    for (int i = 0; i < 8; ++i) {
      short hi_, lo_;
      split_bf16(xs[i] * scale, hi_, lo_);
      qhi[hf][i] = hi_;
      qlo[hf][i] = lo_;
    }
  }

  float4v acc[8];
#pragma unroll
  for (int i = 0; i < 8; ++i) acc[i] = (float4v){0.f, 0.f, 0.f, 0.f};
  float m_run = -INFINITY;
  float l_run = 0.f;

  const int skv = tid >> 4;
  const int shd = (tid & 15) << 3;
  const int vkv = (tid & 15) << 1;
  const int vhd = (tid >> 4) << 2;
  const int ntiles = (qtile + 1) << 2;

  for (int t = 0; t < ntiles; ++t) {
    const int kvb = t << 5;
    __syncthreads();
    {
      const float* kr = Kg + (size_t)(kvb + skv) * row3d + shd;
#pragma unroll
      for (int u = 0; u < 2; ++u) {
        float4 v = *(const float4*)(kr + 4 * u);
        short h0, l0, h1, l1, h2, l2, h3, l3;
        split_bf16(v.x, h0, l0);
        split_bf16(v.y, h1, l1);
        split_bf16(v.z, h2, l2);
        split_bf16(v.w, h3, l3);
        *(int2*)&Khi[skv][shd + 4 * u] =
            make_int2(pack2(h0, h1), pack2(h2, h3));
        *(int2*)&Klo[skv][shd + 4 * u] =
            make_int2(pack2(l0, l1), pack2(l2, l3));
      }
    }
    {
      const float* v0p = Vg + (size_t)(kvb + vkv) * row3d + vhd;
      const float* v1p = v0p + row3d;
      float4 a0 = *(const float4*)(v0p);
      float4 b0 = *(const float4*)(v1p);
      float e0[4] = {a0.x, a0.y, a0.z, a0.w};
      float e1[4] = {b0.x, b0.y, b0.z, b0.w};
#pragma unroll
      for (int e = 0; e < 4; ++e) {
        short h0, l0, h1, l1;
        split_bf16(e0[e], h0, l0);
        split_bf16(e1[e], h1, l1);
        *(int*)&Vthi[vhd + e][vkv] = pack2(h0, h1);
        *(int*)&Vtlo[vhd + e][vkv] = pack2(l0, l1);
      }
    }
    __syncthreads();

    if (kvb <= qw + 15) {
      float4v s4[2];
#pragma unroll
      for (int f = 0; f < 2; ++f) s4[f] = (float4v){0.f, 0.f, 0.f, 0.f};
#pragma unroll
      for (int f = 0; f < 2; ++f) {
#pragma unroll
        for (int hf = 0; hf < 4; ++hf) {
          short8v ka = *(const short8v*)&Khi[16 * f + r][32 * hf + 8 * g];
          short8v kb = *(const short8v*)&Klo[16 * f + r][32 * hf + 8 * g];
          s4[f] = MFMA16(ka, qhi[hf], s4[f]);
          s4[f] = MFMA16(ka, qlo[hf], s4[f]);
          s4[f] = MFMA16(kb, qhi[hf], s4[f]);
        }
      }
      const int qglob = qw + r;
      if (kvb + 31 > qw) {
#pragma unroll
        for (int f = 0; f < 2; ++f)
#pragma unroll
          for (int j = 0; j < 4; ++j)
            if (kvb + 16 * f + 4 * g + j > qglob) s4[f][j] = -INFINITY;
      }
      float tmax = s4[0][0];
#pragma unroll
      for (int f = 0; f < 2; ++f)
#pragma unroll
        for (int j = 0; j < 4; ++j) tmax = fmaxf(tmax, s4[f][j]);
      tmax = fmaxf(tmax, __shfl_xor(tmax, 16));
      tmax = fmaxf(tmax, __shfl_xor(tmax, 32));
      const float mnew = fmaxf(m_run, tmax);
      const float alpha = __expf(m_run - mnew);
      float psum = 0.f;
      short ph[8], pl[8];
#pragma unroll
      for (int f = 0; f < 2; ++f)
#pragma unroll
        for (int j = 0; j < 4; ++j) {
          float p = __expf(s4[f][j] - mnew);
          psum += p;
          split_bf16(p, ph[4 * f + j], pl[4 * f + j]);
        }
      psum += __shfl_xor(psum, 16);
      psum += __shfl_xor(psum, 32);
      l_run = l_run * alpha + psum;
      m_run = mnew;
#pragma unroll
      for (int f = 0; f < 2; ++f) {
        *(int2*)&Phi[wave][r][16 * f + 4 * g] = make_int2(
            pack2(ph[4 * f + 0], ph[4 * f + 1]),
            pack2(ph[4 * f + 2], ph[4 * f + 3]));
        *(int2*)&Plo[wave][r][16 * f + 4 * g] = make_int2(
            pack2(pl[4 * f + 0], pl[4 * f + 1]),
            pack2(pl[4 * f + 2], pl[4 * f + 3]));
      }
      float aj[4];
#pragma unroll
      for (int j = 0; j < 4; ++j) aj[j] = __shfl(alpha, 4 * g + j);
#pragma unroll
      for (int hf = 0; hf < 8; ++hf)
#pragma unroll
        for (int j = 0; j < 4; ++j) acc[hf][j] *= aj[j];
      short8v pa = *(const short8v*)&Phi[wave][r][8 * g];
      short8v pb = *(const short8v*)&Plo[wave][r][8 * g];
#pragma unroll
      for (int hf = 0; hf < 8; ++hf) {
        short8v va = *(const short8v*)&Vthi[16 * hf + r][8 * g];
        short8v vb = *(const short8v*)&Vtlo[16 * hf + r][8 * g];
        acc[hf] = MFMA16(pa, va, acc[hf]);
        acc[hf] = MFMA16(pa, vb, acc[hf]);
        acc[hf] = MFMA16(pb, va, acc[hf]);
      }
    }
  }
  const float il = 1.f / l_run;
  float lj[4];
#pragma unroll
  for (int j = 0; j < 4; ++j) lj[j] = __shfl(il, 4 * g + j);
  const size_t obase = ((size_t)b * NS + qw) * ND + h * HD;
  if (SPLITOUT) {
    short* OhB = Oh + obase;
    short* OlB = Ol + obase;
#pragma unroll
    for (int hf = 0; hf < 8; ++hf)
#pragma unroll
      for (int j = 0; j < 4; ++j) {
        const float v = acc[hf][j] * lj[j];
        short h_, l_;
        split_bf16(v, h_, l_);
        const size_t idx = (size_t)(4 * g + j) * ND + 16 * hf + r;
        OhB[idx] = h_;
        OlB[idx] = l_;
      }
  } else {
    float* Ob = O + obase;
#pragma unroll
    for (int hf = 0; hf < 8; ++hf)
#pragma unroll
      for (int j = 0; j < 4; ++j)
        Ob[(size_t)(4 * g + j) * ND + 16 * hf + r] = acc[hf][j] * lj[j];
  }
}

// ---------------------------------------------------------------------------
// Launch. Full layout 225 MiB: qkv f32 | attn f32 | WqkvT hi/lo | WoT hi/lo
// | rope tab | xh/xl. ath/atl ALIAS xh/xl (x splits dead after QKV GEMM).
// Full path: attention writes ath/atl bf16 DIRECTLY (fused split, bit-
// identical values) — no fp32 attn write, no separate split kernel.
// Fallback tiers: base (202 MiB, inline-split A) -> fp32 GEMMs.
// ---------------------------------------------------------------------------
extern "C" void kernel_launch(void* const* d_in, const int* in_sizes, int n_in,
                              void* d_out, int out_size, void* d_ws,
                              size_t ws_size, hipStream_t stream) {
  const float* x = (const float*)d_in[0];
  const float* Wqkv = (const float*)d_in[1];
  const float* Wo = (const float*)d_in[2];
  float* out = (float*)d_out;
  float* qkv = (float*)d_ws;                       // 25165824 f
  float* attn = qkv + (size_t)NB * NS * 3 * ND;    // 8388608 f
  short* wqh = (short*)(attn + (size_t)NB * NS * ND);  // 12582912 s each
  short* wql = wqh + (size_t)ND * 3 * ND;
  short* woh = wql + (size_t)ND * 3 * ND;          // 4194304 s each
  short* wol = woh + (size_t)ND * ND;
  float2* tab = (float2*)(wol + (size_t)ND * ND);  // 131072 float2
  short* xh = (short*)(tab + (size_t)NS * 64);     // 8388608 s each
  short* xl = xh + (size_t)NB * NS * ND;
  short* ath = xh;  // ALIAS: x splits dead after QKV GEMM
  short* atl = xl;

  const size_t base_need =
      ((size_t)NB * NS * 3 * ND + (size_t)NB * NS * ND) * 4 +
      ((size_t)ND * 3 * ND + (size_t)ND * ND) * 2 * 2 + (size_t)NS * 64 * 8;
  const size_t full_need = base_need + (size_t)NB * NS * ND * 2 * 2;

  const int M = NB * NS;
  if (ws_size >= base_need) {
    rope_table_kernel<<<NS * 64 / 256, 256, 0, stream>>>(tab);
    transpose_split_kernel<<<dim3(3 * ND / 32, ND / 32), 256, 0, stream>>>(
        Wqkv, wqh, wql, ND, 3 * ND);
    transpose_split_kernel<<<dim3(ND / 32, ND / 32), 256, 0, stream>>>(
        Wo, woh, wol, ND, ND);
    if (ws_size >= full_need) {
      split_kernel<<<2048, 256, 0, stream>>>(x, xh, xl, M * ND / 4);
      gemm_bf16x3_kernel<true, true, 12, 16>
          <<<dim3(3 * ND / 128, M / 128), 256, 0, stream>>>(
              nullptr, xh, xl, wqh, wql, qkv, M, 3 * ND, ND, tab);
      flash_attn_mfma<true><<<dim3(16, 32), 512, 0, stream>>>(
          qkv, nullptr, ath, atl);
      gemm_bf16x3_kernel<false, true, 4, 16>
          <<<dim3(ND / 128, M / 128), 256, 0, stream>>>(
              nullptr, ath, atl, woh, wol, out, M, ND, ND, tab);
    } else {
      gemm_bf16x3_kernel<true, false, 0, 0>
          <<<dim3(3 * ND / 128, M / 128), 256, 0, stream>>>(
              x, nullptr, nullptr, wqh, wql, qkv, M, 3 * ND, ND, tab);
      flash_attn_mfma<false><<<dim3(16, 32), 512, 0, stream>>>(
          qkv, attn, nullptr, nullptr);
      gemm_bf16x3_kernel<false, false, 0, 0>
          <<<dim3(ND / 128, M / 128), 256, 0, stream>>>(
              attn, nullptr, nullptr, woh, wol, out, M, ND, ND, tab);
    }
  } else {
    gemm_f32_kernel<true>
        <<<dim3(3 * ND / 128, M / 128), 256, 0, stream>>>(
            x, Wqkv, qkv, M, 3 * ND, ND);
    flash_attn_mfma<false><<<dim3(16, 32), 512, 0, stream>>>(
        qkv, attn, nullptr, nullptr);
    gemm_f32_kernel<false>
        <<<dim3(ND / 128, M / 128), 256, 0, stream>>>(
            attn, Wo, out, M, ND, ND);
  }
}

// Round 15
// 699.753 us; speedup vs baseline: 11.7357x; 1.0147x over previous
//
#include <hip/hip_runtime.h>
#include <cstddef>
#include <cstdint>
#include <math.h>

// Problem constants (B=2, S=2048, D=2048, H=16, hd=128)
#define NB 2
#define NS 2048
#define ND 2048
#define NH 16
#define HD 128

typedef __attribute__((ext_vector_type(8))) short short8v;   // 8 bf16 (4 VGPR)
typedef __attribute__((ext_vector_type(4))) float float4v;   // MFMA acc

#define MFMA16(A, B, C) __builtin_amdgcn_mfma_f32_16x16x32_bf16(A, B, C, 0, 0, 0)

// Split fp32 into bf16 hi + bf16 lo (x ~= hi + lo, rel err ~2^-17).
__device__ __forceinline__ void split_bf16(float x, short& hi, short& lo) {
  unsigned u = __float_as_uint(x);
  unsigned hb = (u + 0x7FFFu + ((u >> 16) & 1u)) >> 16;
  float hif = __uint_as_float(hb << 16);
  float r = x - hif;
  unsigned ul = __float_as_uint(r);
  hi = (short)hb;
  lo = (short)((ul + 0x7FFFu + ((ul >> 16) & 1u)) >> 16);
}

__device__ __forceinline__ int pack2(short a, short b) {
  return (int)(unsigned short)a | ((int)(unsigned short)b << 16);
}

// ---------------------------------------------------------------------------
// FUSED prep kernel (full path): one launch doing
//   [0,512):            rope cos/sin table (131072 entries)
//   [512,12800):        transpose+split Wqkv  (192 x 64 tiles of 32x32)
//   [12800,16896):      transpose+split Wo    (64 x 64 tiles)
//   [16896,18944):      elementwise split of x (grid-stride, 2097152 float4)
// All sub-tasks independent; kernel boundary orders them before the QKV GEMM.
// Bodies are bit-identical to the validated standalone kernels.
// ---------------------------------------------------------------------------
__global__ __launch_bounds__(256) void fused_prep_kernel(
    float2* __restrict__ tab,
    const float* __restrict__ Wqkv, short* __restrict__ wqh,
    short* __restrict__ wql,
    const float* __restrict__ Wo, short* __restrict__ woh,
    short* __restrict__ wol,
    const float* __restrict__ x, short* __restrict__ xh,
    short* __restrict__ xl) {
  __shared__ float T[32][33];
  const int tid = threadIdx.x;
  const int blk = blockIdx.x;
  if (blk < 512) {
    // rope table
    const int id = blk * 256 + tid;
    const int spos = id >> 6, p = id & 63;
    const float invf = powf(10000.f, -(float)p * (1.f / 64.f));
    float s, c;
    sincosf((float)spos * invf, &s, &c);
    tab[id] = make_float2(c, s);
  } else if (blk < 12800) {
    // transpose+split Wqkv: K=ND rows, N=3*ND cols
    const int t = blk - 512;
    const int n0 = (t % 192) * 32, k0 = (t / 192) * 32;
    const int K = ND, N = 3 * ND;
    {
      const int r = tid >> 3, c4 = (tid & 7) << 2;
      float4 v = *(const float4*)&Wqkv[(size_t)(k0 + r) * N + n0 + c4];
      T[r][c4 + 0] = v.x;
      T[r][c4 + 1] = v.y;
      T[r][c4 + 2] = v.z;
      T[r][c4 + 3] = v.w;
    }
    __syncthreads();
    const int n = tid >> 3, k4 = (tid & 7) << 2;
    short h[4], l[4];
#pragma unroll
    for (int e = 0; e < 4; ++e) split_bf16(T[k4 + e][n], h[e], l[e]);
    const size_t off = (size_t)(n0 + n) * K + k0 + k4;
    *(int2*)&wqh[off] = make_int2(pack2(h[0], h[1]), pack2(h[2], h[3]));
    *(int2*)&wql[off] = make_int2(pack2(l[0], l[1]), pack2(l[2], l[3]));
  } else if (blk < 16896) {
    // transpose+split Wo: K=ND rows, N=ND cols
    const int t = blk - 12800;
    const int n0 = (t % 64) * 32, k0 = (t / 64) * 32;
    const int K = ND, N = ND;
    {
      const int r = tid >> 3, c4 = (tid & 7) << 2;
      float4 v = *(const float4*)&Wo[(size_t)(k0 + r) * N + n0 + c4];
      T[r][c4 + 0] = v.x;
      T[r][c4 + 1] = v.y;
      T[r][c4 + 2] = v.z;
      T[r][c4 + 3] = v.w;
    }
    __syncthreads();
    const int n = tid >> 3, k4 = (tid & 7) << 2;
    short h[4], l[4];
#pragma unroll
    for (int e = 0; e < 4; ++e) split_bf16(T[k4 + e][n], h[e], l[e]);
    const size_t off = (size_t)(n0 + n) * K + k0 + k4;
    *(int2*)&woh[off] = make_int2(pack2(h[0], h[1]), pack2(h[2], h[3]));
    *(int2*)&wol[off] = make_int2(pack2(l[0], l[1]), pack2(l[2], l[3]));
  } else {
    // split x: n4 = NB*NS*ND/4 float4s, grid-stride over 2048 blocks
    const int n4 = NB * NS * ND / 4;
    for (int i = (blk - 16896) * 256 + tid; i < n4; i += 2048 * 256) {
      float4 v = ((const float4*)x)[i];
      short h0, l0, h1, l1, h2, l2, h3, l3;
      split_bf16(v.x, h0, l0);
      split_bf16(v.y, h1, l1);
      split_bf16(v.z, h2, l2);
      split_bf16(v.w, h3, l3);
      ((int2*)xh)[i] = make_int2(pack2(h0, h1), pack2(h2, h3));
      ((int2*)xl)[i] = make_int2(pack2(l0, l1), pack2(l2, l3));
    }
  }
}

// ---------------------------------------------------------------------------
// Standalone prep kernels (fallback paths; validated round-8 versions).
// ---------------------------------------------------------------------------
__global__ __launch_bounds__(256) void rope_table_kernel(float2* tab) {
  const int id = blockIdx.x * 256 + threadIdx.x;  // 131072 total
  const int spos = id >> 6, p = id & 63;
  const float invf = powf(10000.f, -(float)p * (1.f / 64.f));
  float s, c;
  sincosf((float)spos * invf, &s, &c);
  tab[id] = make_float2(c, s);
}

__global__ __launch_bounds__(256) void transpose_split_kernel(
    const float* __restrict__ W, short* __restrict__ Th, short* __restrict__ Tl,
    int K, int N) {
  __shared__ float T[32][33];
  const int tid = threadIdx.x;
  const int n0 = blockIdx.x * 32, k0 = blockIdx.y * 32;
  {
    const int r = tid >> 3, c4 = (tid & 7) << 2;
    float4 v = *(const float4*)&W[(size_t)(k0 + r) * N + n0 + c4];
    T[r][c4 + 0] = v.x;
    T[r][c4 + 1] = v.y;
    T[r][c4 + 2] = v.z;
    T[r][c4 + 3] = v.w;
  }
  __syncthreads();
  const int n = tid >> 3, k4 = (tid & 7) << 2;
  short h[4], l[4];
#pragma unroll
  for (int e = 0; e < 4; ++e) split_bf16(T[k4 + e][n], h[e], l[e]);
  const size_t off = (size_t)(n0 + n) * K + k0 + k4;
  *(int2*)&Th[off] = make_int2(pack2(h[0], h[1]), pack2(h[2], h[3]));
  *(int2*)&Tl[off] = make_int2(pack2(l[0], l[1]), pack2(l[2], l[3]));
}

// ---------------------------------------------------------------------------
// Split-bf16 MFMA GEMM (validated round-12/13 kernel, unchanged).
// ---------------------------------------------------------------------------
template <bool ROPE, bool ASPLIT, int CHX, int CHY>
__global__ __launch_bounds__(256) void gemm_bf16x3_kernel(
    const float* __restrict__ Af, const short* __restrict__ Ahg,
    const short* __restrict__ Alg, const short* __restrict__ BTh,
    const short* __restrict__ BTl, float* __restrict__ C, int M, int N, int K,
    const float2* __restrict__ rope_tab) {
  __shared__ short Ah[128][40], Al[128][40];
  __shared__ short Bh[128][40], Bl[128][40];
  const int tid = threadIdx.x;
  const int wave = tid >> 6, lane = tid & 63;
  const int g = lane >> 4, r = lane & 15;
  const int wy = wave >> 1, wx = wave & 1;

  int bx = blockIdx.x, by = blockIdx.y;
  if (CHX > 0) {  // XCD-aware 2D chunk swizzle (bijective)
    const int flat = by * gridDim.x + bx;
    const int xcd = flat & 7, idx = flat >> 3;
    bx = (xcd & 3) * CHX + idx % CHX;
    by = (xcd >> 2) * CHY + idx / CHX;
  }
  const int m0 = by * 128, n0 = bx * 128;
  const int wm = wy * 64, wn = wx * 64;

  // staging maps: 2 threads per row, 16 elements each
  const int ar = tid >> 1, ac = (tid & 1) << 4;

  const short* bhp = BTh + (size_t)(n0 + ar) * K + ac;
  const short* blp = BTl + (size_t)(n0 + ar) * K + ac;

  float4v acc[4][4];
#pragma unroll
  for (int i = 0; i < 4; ++i)
#pragma unroll
    for (int j = 0; j < 4; ++j) acc[i][j] = (float4v){0.f, 0.f, 0.f, 0.f};

  // prologue: chunk 0 loads
  float4 a0, a1, a2, a3;
  int4 ah0, ah1, al0, al1;
  const float* aptr = nullptr;
  const short* ahp = nullptr;
  const short* alp = nullptr;
  if (ASPLIT) {
    ahp = Ahg + (size_t)(m0 + ar) * K + ac;
    alp = Alg + (size_t)(m0 + ar) * K + ac;
    ah0 = *(const int4*)(ahp);
    ah1 = *(const int4*)(ahp + 8);
    al0 = *(const int4*)(alp);
    al1 = *(const int4*)(alp + 8);
  } else {
    aptr = Af + (size_t)(m0 + ar) * K + ac;
    a0 = *(const float4*)(aptr);
    a1 = *(const float4*)(aptr + 4);
    a2 = *(const float4*)(aptr + 8);
    a3 = *(const float4*)(aptr + 12);
  }
  int4 bh0 = *(const int4*)(bhp);
  int4 bh1 = *(const int4*)(bhp + 8);
  int4 bl0 = *(const int4*)(blp);
  int4 bl1 = *(const int4*)(blp + 8);

  for (int k0 = 0; k0 < K; k0 += 32) {
    __syncthreads();  // previous chunk consumed
    if (ASPLIT) {
      *(int4*)&Ah[ar][ac] = ah0;
      *(int4*)&Ah[ar][ac + 8] = ah1;
      *(int4*)&Al[ar][ac] = al0;
      *(int4*)&Al[ar][ac + 8] = al1;
    } else {
      float xs[16] = {a0.x, a0.y, a0.z, a0.w, a1.x, a1.y, a1.z, a1.w,
                      a2.x, a2.y, a2.z, a2.w, a3.x, a3.y, a3.z, a3.w};
      short h[16], l[16];
#pragma unroll
      for (int e = 0; e < 16; ++e) split_bf16(xs[e], h[e], l[e]);
      *(int4*)&Ah[ar][ac] =
          make_int4(pack2(h[0], h[1]), pack2(h[2], h[3]), pack2(h[4], h[5]),
                    pack2(h[6], h[7]));
      *(int4*)&Ah[ar][ac + 8] =
          make_int4(pack2(h[8], h[9]), pack2(h[10], h[11]),
                    pack2(h[12], h[13]), pack2(h[14], h[15]));
      *(int4*)&Al[ar][ac] =
          make_int4(pack2(l[0], l[1]), pack2(l[2], l[3]), pack2(l[4], l[5]),
                    pack2(l[6], l[7]));
      *(int4*)&Al[ar][ac + 8] =
          make_int4(pack2(l[8], l[9]), pack2(l[10], l[11]),
                    pack2(l[12], l[13]), pack2(l[14], l[15]));
    }
    *(int4*)&Bh[ar][ac] = bh0;
    *(int4*)&Bh[ar][ac + 8] = bh1;
    *(int4*)&Bl[ar][ac] = bl0;
    *(int4*)&Bl[ar][ac + 8] = bl1;
    __syncthreads();
    if (k0 + 32 < K) {  // prefetch next chunk
      if (ASPLIT) {
        ah0 = *(const int4*)(ahp + k0 + 32);
        ah1 = *(const int4*)(ahp + k0 + 40);
        al0 = *(const int4*)(alp + k0 + 32);
        al1 = *(const int4*)(alp + k0 + 40);
      } else {
        const float* an = aptr + k0 + 32;
        a0 = *(const float4*)(an);
        a1 = *(const float4*)(an + 4);
        a2 = *(const float4*)(an + 8);
        a3 = *(const float4*)(an + 12);
      }
      bh0 = *(const int4*)(bhp + k0 + 32);
      bh1 = *(const int4*)(bhp + k0 + 40);
      bl0 = *(const int4*)(blp + k0 + 32);
      bl1 = *(const int4*)(blp + k0 + 40);
    }
    // fragments + MFMA
    short8v afh[4], afl[4], bfh[4], bfl[4];
#pragma unroll
    for (int mi = 0; mi < 4; ++mi) {
      afh[mi] = *(const short8v*)&Ah[wm + mi * 16 + r][8 * g];
      afl[mi] = *(const short8v*)&Al[wm + mi * 16 + r][8 * g];
    }
#pragma unroll
    for (int nj = 0; nj < 4; ++nj) {
      bfh[nj] = *(const short8v*)&Bh[wn + nj * 16 + r][8 * g];
      bfl[nj] = *(const short8v*)&Bl[wn + nj * 16 + r][8 * g];
    }
#pragma unroll
    for (int mi = 0; mi < 4; ++mi)
#pragma unroll
      for (int nj = 0; nj < 4; ++nj) {
        acc[mi][nj] = MFMA16(afh[mi], bfh[nj], acc[mi][nj]);
        acc[mi][nj] = MFMA16(afh[mi], bfl[nj], acc[mi][nj]);
        acc[mi][nj] = MFMA16(afl[mi], bfh[nj], acc[mi][nj]);
      }
  }

  if (ROPE && n0 < 2 * ND) {  // q,k slabs only (v passthrough)
    int p[4];
#pragma unroll
    for (int nj = 0; nj < 4; ++nj)
      p[nj] = ((n0 + wn + nj * 16 + r) & (HD - 1)) >> 1;
    const bool even = (r & 1) == 0;
#pragma unroll
    for (int mi = 0; mi < 4; ++mi)
#pragma unroll
      for (int j = 0; j < 4; ++j) {
        const int spos = (m0 + wm + mi * 16 + 4 * g + j) & (NS - 1);
#pragma unroll
        for (int nj = 0; nj < 4; ++nj) {
          const float2 cs = rope_tab[spos * 64 + p[nj]];
          const float own = acc[mi][nj][j];
          const float oth = __shfl_xor(own, 1);
          acc[mi][nj][j] = even ? own * cs.x - oth * cs.y
                                : oth * cs.y + own * cs.x;
        }
      }
  }
#pragma unroll
  for (int mi = 0; mi < 4; ++mi)
#pragma unroll
    for (int j = 0; j < 4; ++j) {
      const size_t row = m0 + wm + mi * 16 + 4 * g + j;
      float* Crow = C + row * N + n0 + wn;
#pragma unroll
      for (int nj = 0; nj < 4; ++nj) Crow[nj * 16 + r] = acc[mi][nj][j];
    }
}

// ---------------------------------------------------------------------------
// Fallback tiled fp32 GEMM (validated round-5/6 kernel, unchanged).
// ---------------------------------------------------------------------------
template <bool ROPE>
__global__ __launch_bounds__(256) void gemm_f32_kernel(
    const float* __restrict__ A, const float* __restrict__ Bm,
    float* __restrict__ C, int M, int N, int K) {
  __shared__ float As[16][132];
  __shared__ float Bs[16][132];
  const int tid = threadIdx.x;
  const int m0 = blockIdx.y * 128;
  const int n0 = blockIdx.x * 128;
  const int tr = tid >> 4;
  const int tc = tid & 15;
  const int la_r = tid >> 1;
  const int la_c = (tid & 1) << 3;
  const int lb_r = tid >> 4;
  const int lb_c = (tid & 15) << 3;

  const float* Aptr = A + (size_t)(m0 + la_r) * K + la_c;
  const float* Bptr = Bm + (size_t)lb_r * N + n0 + lb_c;

  float acc[8][8] = {};

  float4 av0 = *(const float4*)(Aptr);
  float4 av1 = *(const float4*)(Aptr + 4);
  float4 bv0 = *(const float4*)(Bptr);
  float4 bv1 = *(const float4*)(Bptr + 4);

  for (int k0 = 0; k0 < K; k0 += 16) {
    __syncthreads();
    As[la_c + 0][la_r] = av0.x;
    As[la_c + 1][la_r] = av0.y;
    As[la_c + 2][la_r] = av0.z;
    As[la_c + 3][la_r] = av0.w;
    As[la_c + 4][la_r] = av1.x;
    As[la_c + 5][la_r] = av1.y;
    As[la_c + 6][la_r] = av1.z;
    As[la_c + 7][la_r] = av1.w;
    *(float4*)&Bs[lb_r][lb_c] = bv0;
    *(float4*)&Bs[lb_r][lb_c + 4] = bv1;
    __syncthreads();
    if (k0 + 16 < K) {
      const float* An = Aptr + k0 + 16;
      const float* Bn = Bptr + (size_t)(k0 + 16) * N;
      av0 = *(const float4*)(An);
      av1 = *(const float4*)(An + 4);
      bv0 = *(const float4*)(Bn);
      bv1 = *(const float4*)(Bn + 4);
    }
#pragma unroll
    for (int kk = 0; kk < 16; ++kk) {
      float a[8], b[8];
      *(float4*)&a[0] = *(const float4*)&As[kk][tr << 2];
      *(float4*)&a[4] = *(const float4*)&As[kk][64 + (tr << 2)];
      *(float4*)&b[0] = *(const float4*)&Bs[kk][tc << 2];
      *(float4*)&b[4] = *(const float4*)&Bs[kk][64 + (tc << 2)];
#pragma unroll
      for (int i = 0; i < 8; ++i)
#pragma unroll
        for (int j = 0; j < 8; ++j) acc[i][j] = fmaf(a[i], b[j], acc[i][j]);
    }
  }

  if (ROPE) {
    if ((n0 >> 11) < 2) {
#pragma unroll
      for (int g = 0; g < 2; ++g) {
        const int col = n0 + g * 64 + (tc << 2);
        const int d0 = col & (HD - 1);
        const int p0 = d0 >> 1;
        const float invf0 = powf(10000.f, -(float)p0 * (1.f / 64.f));
        const float invf1 = powf(10000.f, -(float)(p0 + 1) * (1.f / 64.f));
#pragma unroll
        for (int rg = 0; rg < 2; ++rg) {
#pragma unroll
          for (int i = 0; i < 4; ++i) {
            const int row = m0 + rg * 64 + (tr << 2) + i;
            const int spos = row & (NS - 1);
            float s0, c0, s1, c1;
            sincosf((float)spos * invf0, &s0, &c0);
            sincosf((float)spos * invf1, &s1, &c1);
            float* ar2 = &acc[rg * 4 + i][g * 4];
            const float xe0 = ar2[0], xo0 = ar2[1];
            const float xe1 = ar2[2], xo1 = ar2[3];
            ar2[0] = xe0 * c0 - xo0 * s0;
            ar2[1] = xe0 * s0 + xo0 * c0;
            ar2[2] = xe1 * c1 - xo1 * s1;
            ar2[3] = xe1 * s1 + xo1 * c1;
          }
        }
      }
    }
  }
#pragma unroll
  for (int rg = 0; rg < 2; ++rg) {
#pragma unroll
    for (int i = 0; i < 4; ++i) {
      const size_t row = m0 + rg * 64 + (tr << 2) + i;
      float* Crow = C + row * N + n0;
      float4 v0 = make_float4(acc[rg * 4 + i][0], acc[rg * 4 + i][1],
                              acc[rg * 4 + i][2], acc[rg * 4 + i][3]);
      float4 v1 = make_float4(acc[rg * 4 + i][4], acc[rg * 4 + i][5],
                              acc[rg * 4 + i][6], acc[rg * 4 + i][7]);
      *(float4*)(Crow + (tc << 2)) = v0;
      *(float4*)(Crow + 64 + (tc << 2)) = v1;
    }
  }
}

// ---------------------------------------------------------------------------
// Flash attention via split-bf16 MFMA (validated round-13 kernel, unchanged).
// SPLITOUT: write output directly as bf16 hi/lo pair (bit-identical to
// fp32-write + separate split kernel) — feeds the out-GEMM's ASPLIT path.
// ---------------------------------------------------------------------------
template <bool SPLITOUT>
__global__ __launch_bounds__(512) void flash_attn_mfma(
    const float* __restrict__ qkv, float* __restrict__ O,
    short* __restrict__ Oh, short* __restrict__ Ol) {
  __shared__ short Khi[32][136];
  __shared__ short Klo[32][136];
  __shared__ short Vthi[128][40];
  __shared__ short Vtlo[128][40];
  __shared__ short Phi[8][16][40];
  __shared__ short Plo[8][16][40];

  const int tid = threadIdx.x;
  const int lane = tid & 63;
  const int wave = tid >> 6;
  const int g = lane >> 4;
  const int r = lane & 15;
  const int qtile = 15 - blockIdx.x;
  const int bh = blockIdx.y;
  const int b = bh >> 4, h = bh & 15;
  const int qb = qtile << 7;
  const int qw = qb + (wave << 4);
  const size_t row3d = 3 * ND;
  const float* base = qkv + (size_t)b * NS * row3d + (size_t)h * HD;
  const float* Kg = base + ND;
  const float* Vg = base + 2 * ND;

  const float scale = 0.088388347648318447f;
  const float* Qrow = base + (size_t)(qw + r) * row3d;
  short8v qhi[4], qlo[4];
#pragma unroll
  for (int hf = 0; hf < 4; ++hf) {
    const float* p = Qrow + 32 * hf + 8 * g;
    float4 x0 = *(const float4*)(p);
    float4 x1 = *(const float4*)(p + 4);
    float xs[8] = {x0.x, x0.y, x0.z, x0.w, x1.x, x1.y, x1.z, x1.w};
#pragma unroll
    for (int i = 0; i < 8; ++i) {
      short hi_, lo_;
      split_bf16(xs[i] * scale, hi_, lo_);
      qhi[hf][i] = hi_;
      qlo[hf][i] = lo_;
    }
  }

  float4v acc[8];
#pragma unroll
  for (int i = 0; i < 8; ++i) acc[i] = (float4v){0.f, 0.f, 0.f, 0.f};
  float m_run = -INFINITY;
  float l_run = 0.f;

  const int skv = tid >> 4;
  const int shd = (tid & 15) << 3;
  const int vkv = (tid & 15) << 1;
  const int vhd = (tid >> 4) << 2;
  const int ntiles = (qtile + 1) << 2;

  for (int t = 0; t < ntiles; ++t) {
    const int kvb = t << 5;
    __syncthreads();
    {
      const float* kr = Kg + (size_t)(kvb + skv) * row3d + shd;
#pragma unroll
      for (int u = 0; u < 2; ++u) {
        float4 v = *(const float4*)(kr + 4 * u);
        short h0, l0, h1, l1, h2, l2, h3, l3;
        split_bf16(v.x, h0, l0);
        split_bf16(v.y, h1, l1);
        split_bf16(v.z, h2, l2);
        split_bf16(v.w, h3, l3);
        *(int2*)&Khi[skv][shd + 4 * u] =
            make_int2(pack2(h0, h1), pack2(h2, h3));
        *(int2*)&Klo[skv][shd + 4 * u] =
            make_int2(pack2(l0, l1), pack2(l2, l3));
      }
    }
    {
      const float* v0p = Vg + (size_t)(kvb + vkv) * row3d + vhd;
      const float* v1p = v0p + row3d;
      float4 a0 = *(const float4*)(v0p);
      float4 b0 = *(const float4*)(v1p);
      float e0[4] = {a0.x, a0.y, a0.z, a0.w};
      float e1[4] = {b0.x, b0.y, b0.z, b0.w};
#pragma unroll
      for (int e = 0; e < 4; ++e) {
        short h0, l0, h1, l1;
        split_bf16(e0[e], h0, l0);
        split_bf16(e1[e], h1, l1);
        *(int*)&Vthi[vhd + e][vkv] = pack2(h0, h1);
        *(int*)&Vtlo[vhd + e][vkv] = pack2(l0, l1);
      }
    }
    __syncthreads();

    if (kvb <= qw + 15) {
      float4v s4[2];
#pragma unroll
      for (int f = 0; f < 2; ++f) s4[f] = (float4v){0.f, 0.f, 0.f, 0.f};
#pragma unroll
      for (int f = 0; f < 2; ++f) {
#pragma unroll
        for (int hf = 0; hf < 4; ++hf) {
          short8v ka = *(const short8v*)&Khi[16 * f + r][32 * hf + 8 * g];
          short8v kb = *(const short8v*)&Klo[16 * f + r][32 * hf + 8 * g];
          s4[f] = MFMA16(ka, qhi[hf], s4[f]);
          s4[f] = MFMA16(ka, qlo[hf], s4[f]);
          s4[f] = MFMA16(kb, qhi[hf], s4[f]);
        }
      }
      const int qglob = qw + r;
      if (kvb + 31 > qw) {
#pragma unroll
        for (int f = 0; f < 2; ++f)
#pragma unroll
          for (int j = 0; j < 4; ++j)
            if (kvb + 16 * f + 4 * g + j > qglob) s4[f][j] = -INFINITY;
      }
      float tmax = s4[0][0];
#pragma unroll
      for (int f = 0; f < 2; ++f)
#pragma unroll
        for (int j = 0; j < 4; ++j) tmax = fmaxf(tmax, s4[f][j]);
      tmax = fmaxf(tmax, __shfl_xor(tmax, 16));
      tmax = fmaxf(tmax, __shfl_xor(tmax, 32));
      const float mnew = fmaxf(m_run, tmax);
      const float alpha = __expf(m_run - mnew);
      float psum = 0.f;
      short ph[8], pl[8];
#pragma unroll
      for (int f = 0; f < 2; ++f)
#pragma unroll
        for (int j = 0; j < 4; ++j) {
          float p = __expf(s4[f][j] - mnew);
          psum += p;
          split_bf16(p, ph[4 * f + j], pl[4 * f + j]);
        }
      psum += __shfl_xor(psum, 16);
      psum += __shfl_xor(psum, 32);
      l_run = l_run * alpha + psum;
      m_run = mnew;
#pragma unroll
      for (int f = 0; f < 2; ++f) {
        *(int2*)&Phi[wave][r][16 * f + 4 * g] = make_int2(
            pack2(ph[4 * f + 0], ph[4 * f + 1]),
            pack2(ph[4 * f + 2], ph[4 * f + 3]));
        *(int2*)&Plo[wave][r][16 * f + 4 * g] = make_int2(
            pack2(pl[4 * f + 0], pl[4 * f + 1]),
            pack2(pl[4 * f + 2], pl[4 * f + 3]));
      }
      float aj[4];
#pragma unroll
      for (int j = 0; j < 4; ++j) aj[j] = __shfl(alpha, 4 * g + j);
#pragma unroll
      for (int hf = 0; hf < 8; ++hf)
#pragma unroll
        for (int j = 0; j < 4; ++j) acc[hf][j] *= aj[j];
      short8v pa = *(const short8v*)&Phi[wave][r][8 * g];
      short8v pb = *(const short8v*)&Plo[wave][r][8 * g];
#pragma unroll
      for (int hf = 0; hf < 8; ++hf) {
        short8v va = *(const short8v*)&Vthi[16 * hf + r][8 * g];
        short8v vb = *(const short8v*)&Vtlo[16 * hf + r][8 * g];
        acc[hf] = MFMA16(pa, va, acc[hf]);
        acc[hf] = MFMA16(pa, vb, acc[hf]);
        acc[hf] = MFMA16(pb, va, acc[hf]);
      }
    }
  }
  const float il = 1.f / l_run;
  float lj[4];
#pragma unroll
  for (int j = 0; j < 4; ++j) lj[j] = __shfl(il, 4 * g + j);
  const size_t obase = ((size_t)b * NS + qw) * ND + h * HD;
  if (SPLITOUT) {
    short* OhB = Oh + obase;
    short* OlB = Ol + obase;
#pragma unroll
    for (int hf = 0; hf < 8; ++hf)
#pragma unroll
      for (int j = 0; j < 4; ++j) {
        const float v = acc[hf][j] * lj[j];
        short h_, l_;
        split_bf16(v, h_, l_);
        const size_t idx = (size_t)(4 * g + j) * ND + 16 * hf + r;
        OhB[idx] = h_;
        OlB[idx] = l_;
      }
  } else {
    float* Ob = O + obase;
#pragma unroll
    for (int hf = 0; hf < 8; ++hf)
#pragma unroll
      for (int j = 0; j < 4; ++j)
        Ob[(size_t)(4 * g + j) * ND + 16 * hf + r] = acc[hf][j] * lj[j];
  }
}

// ---------------------------------------------------------------------------
// Launch. Full layout 225 MiB: qkv f32 | attn f32 | WqkvT hi/lo | WoT hi/lo
// | rope tab | xh/xl. ath/atl ALIAS xh/xl (x splits dead after QKV GEMM).
// Full path: ONE fused prep kernel (table + both W transposes + x split),
// then QKV GEMM -> attention (bf16 split output) -> out GEMM. 4 launches.
// Fallback tiers: base (202 MiB, inline-split A) -> fp32 GEMMs.
// ---------------------------------------------------------------------------
extern "C" void kernel_launch(void* const* d_in, const int* in_sizes, int n_in,
                              void* d_out, int out_size, void* d_ws,
                              size_t ws_size, hipStream_t stream) {
  const float* x = (const float*)d_in[0];
  const float* Wqkv = (const float*)d_in[1];
  const float* Wo = (const float*)d_in[2];
  float* out = (float*)d_out;
  float* qkv = (float*)d_ws;                       // 25165824 f
  float* attn = qkv + (size_t)NB * NS * 3 * ND;    // 8388608 f
  short* wqh = (short*)(attn + (size_t)NB * NS * ND);  // 12582912 s each
  short* wql = wqh + (size_t)ND * 3 * ND;
  short* woh = wql + (size_t)ND * 3 * ND;          // 4194304 s each
  short* wol = woh + (size_t)ND * ND;
  float2* tab = (float2*)(wol + (size_t)ND * ND);  // 131072 float2
  short* xh = (short*)(tab + (size_t)NS * 64);     // 8388608 s each
  short* xl = xh + (size_t)NB * NS * ND;
  short* ath = xh;  // ALIAS: x splits dead after QKV GEMM
  short* atl = xl;

  const size_t base_need =
      ((size_t)NB * NS * 3 * ND + (size_t)NB * NS * ND) * 4 +
      ((size_t)ND * 3 * ND + (size_t)ND * ND) * 2 * 2 + (size_t)NS * 64 * 8;
  const size_t full_need = base_need + (size_t)NB * NS * ND * 2 * 2;

  const int M = NB * NS;
  if (ws_size >= full_need) {
    fused_prep_kernel<<<18944, 256, 0, stream>>>(
        tab, Wqkv, wqh, wql, Wo, woh, wol, x, xh, xl);
    gemm_bf16x3_kernel<true, true, 12, 16>
        <<<dim3(3 * ND / 128, M / 128), 256, 0, stream>>>(
            nullptr, xh, xl, wqh, wql, qkv, M, 3 * ND, ND, tab);
    flash_attn_mfma<true><<<dim3(16, 32), 512, 0, stream>>>(
        qkv, nullptr, ath, atl);
    gemm_bf16x3_kernel<false, true, 4, 16>
        <<<dim3(ND / 128, M / 128), 256, 0, stream>>>(
            nullptr, ath, atl, woh, wol, out, M, ND, ND, tab);
  } else if (ws_size >= base_need) {
    rope_table_kernel<<<NS * 64 / 256, 256, 0, stream>>>(tab);
    transpose_split_kernel<<<dim3(3 * ND / 32, ND / 32), 256, 0, stream>>>(
        Wqkv, wqh, wql, ND, 3 * ND);
    transpose_split_kernel<<<dim3(ND / 32, ND / 32), 256, 0, stream>>>(
        Wo, woh, wol, ND, ND);
    gemm_bf16x3_kernel<true, false, 0, 0>
        <<<dim3(3 * ND / 128, M / 128), 256, 0, stream>>>(
            x, nullptr, nullptr, wqh, wql, qkv, M, 3 * ND, ND, tab);
    flash_attn_mfma<false><<<dim3(16, 32), 512, 0, stream>>>(
        qkv, attn, nullptr, nullptr);
    gemm_bf16x3_kernel<false, false, 0, 0>
        <<<dim3(ND / 128, M / 128), 256, 0, stream>>>(
            attn, nullptr, nullptr, woh, wol, out, M, ND, ND, tab);
  } else {
    gemm_f32_kernel<true>
        <<<dim3(3 * ND / 128, M / 128), 256, 0, stream>>>(
            x, Wqkv, qkv, M, 3 * ND, ND);
    flash_attn_mfma<false><<<dim3(16, 32), 512, 0, stream>>>(
        qkv, attn, nullptr, nullptr);
    gemm_f32_kernel<false>
        <<<dim3(ND / 128, M / 128), 256, 0, stream>>>(
            attn, Wo, out, M, ND, ND);
  }
}